// Round 16
// baseline (385.621 us; speedup 1.0000x reference)
//
#include <hip/hip_runtime.h>
#include <hip/hip_bf16.h>
#include <stdint.h>
#include <math.h>

#define H_ 12
#define NQ 196
#define CD 768
#define HIDD 3072
#define VX 8
#define VY 8
#define BB 4
#define MV 4
#define VBB 32
#define ROWS 6272          // VBB*NQ
#define CROSS_ROWS 25088   // VX*MV*BB*NQ
// 0.125 * log2(e): folded into Q by the producing GEMM (EPI 5)
#define SCALE_LOG2E 0.180336880260608f

typedef __attribute__((ext_vector_type(8))) short short8;
typedef __attribute__((ext_vector_type(4))) float f32x4;
typedef __attribute__((ext_vector_type(4))) unsigned short u16x4;
typedef unsigned short u16;

#define AS1 __attribute__((address_space(1)))
#define AS3 __attribute__((address_space(3)))

__device__ __forceinline__ float bf2f(u16 u){
  union { unsigned int i; float f; } v; v.i = ((unsigned int)u) << 16; return v.f;
}
__device__ __forceinline__ u16 f2bf(float f){
  union { unsigned int i; float f; } v; v.f = f;
  return (u16)((v.i + 0x7fff + ((v.i >> 16) & 1)) >> 16);  // RNE
}
__device__ __forceinline__ unsigned int f2u(float f){
  union { unsigned int i; float f; } v; v.f = f; return v.i;
}

// ---------------- fused weight cast f32 -> bf16 (8 segments, 1 dispatch) ----------------
struct CastSegs {
  const float* src[8];
  u16* dst[8];
  int cum[9];   // cumulative element counts, cum[0]=0
};
__global__ __launch_bounds__(256) void k_cast_all(CastSegs segs){
  int i = blockIdx.x * 256 + threadIdx.x;
  if (i >= segs.cum[8]) return;
  int s = 0;
  #pragma unroll
  for (int k = 1; k < 8; k++) s += (i >= segs.cum[k]);
  const int off = i - segs.cum[s];
  segs.dst[s][off] = f2bf(segs.src[s][off]);
}

// ---------------- LayerNorm (f32 in, bf16 out), C=768 fixed ----------------
__device__ __forceinline__ void ln_row(const float* __restrict__ x,
    const float* __restrict__ w, const float* __restrict__ b,
    u16* __restrict__ out, int row, int tid){
  const float* xr = x + (size_t)row * CD;
  float v0 = xr[tid], v1 = xr[tid + 256], v2 = xr[tid + 512];
  float s  = v0 + v1 + v2;
  float s2 = v0*v0 + v1*v1 + v2*v2;
  __shared__ float red[8];
  const int lane = tid & 63, wid = tid >> 6;
  #pragma unroll
  for (int o = 32; o; o >>= 1){ s += __shfl_down(s, o); s2 += __shfl_down(s2, o); }
  if (lane == 0){ red[wid] = s; red[wid + 4] = s2; }
  __syncthreads();
  if (tid == 0){
    red[0] = red[0] + red[1] + red[2] + red[3];
    red[4] = red[4] + red[5] + red[6] + red[7];
  }
  __syncthreads();
  const float mu   = red[0] * (1.f/768.f);
  const float var  = red[4] * (1.f/768.f) - mu*mu;
  const float rstd = rsqrtf(var + 1e-5f);
  u16* orow = out + (size_t)row * CD;
  orow[tid]       = f2bf((v0 - mu)*rstd*w[tid]       + b[tid]);
  orow[tid + 256] = f2bf((v1 - mu)*rstd*w[tid + 256] + b[tid + 256]);
  orow[tid + 512] = f2bf((v2 - mu)*rstd*w[tid + 512] + b[tid + 512]);
}

__global__ __launch_bounds__(256) void k_ln_bf16(const float* __restrict__ x,
    const float* __restrict__ w, const float* __restrict__ b, u16* __restrict__ out){
  ln_row(x, w, b, out, blockIdx.x, threadIdx.x);
}

// two independent LNs in one dispatch (cross block: ln2(x) and lny(ys))
__global__ __launch_bounds__(256) void k_ln_bf16x2(
    const float* __restrict__ x0, const float* __restrict__ w0,
    const float* __restrict__ b0, u16* __restrict__ o0,
    const float* __restrict__ x1, const float* __restrict__ w1,
    const float* __restrict__ b1, u16* __restrict__ o1){
  const int bid = blockIdx.x;
  if (bid < ROWS) ln_row(x0, w0, b0, o0, bid, threadIdx.x);
  else            ln_row(x1, w1, b1, o1, bid - ROWS, threadIdx.x);
}

// ---------------- fused max-over-M + residual-add + LayerNorm ----------------
__global__ __launch_bounds__(256) void k_mmln(const u16* __restrict__ op,
    float* __restrict__ x, const float* __restrict__ w, const float* __restrict__ b,
    u16* __restrict__ out){
  const int row = blockIdx.x, tid = threadIdx.x;
  const int n = row % NQ, vb = row / NQ;
  const int vx = vb >> 2, bb = vb & 3;
  const size_t r0 = ((size_t)(vx * MV) * BB + bb) * NQ + n;  // m=0 source row
  const size_t ms = (size_t)BB * NQ;                          // row step per m
  float* xr = x + (size_t)row * CD;
  float v[3], s = 0.f, s2 = 0.f;
  #pragma unroll
  for (int j = 0; j < 3; j++){
    const int col = tid + j*256;
    float mx =        bf2f(op[(r0       ) * CD + col]);
    mx = fmaxf(mx,    bf2f(op[(r0 +   ms) * CD + col]));
    mx = fmaxf(mx,    bf2f(op[(r0 + 2*ms) * CD + col]));
    mx = fmaxf(mx,    bf2f(op[(r0 + 3*ms) * CD + col]));
    const float val = xr[col] + mx;
    xr[col] = val;
    v[j] = val;
    s += val; s2 += val*val;
  }
  __shared__ float red[8];
  const int lane = tid & 63, wid = tid >> 6;
  #pragma unroll
  for (int o = 32; o; o >>= 1){ s += __shfl_down(s, o); s2 += __shfl_down(s2, o); }
  if (lane == 0){ red[wid] = s; red[wid + 4] = s2; }
  __syncthreads();
  if (tid == 0){
    red[0] = red[0] + red[1] + red[2] + red[3];
    red[4] = red[4] + red[5] + red[6] + red[7];
  }
  __syncthreads();
  const float mu   = red[0] * (1.f/768.f);
  const float var  = red[4] * (1.f/768.f) - mu*mu;
  const float rstd = rsqrtf(var + 1e-5f);
  u16* orow = out + (size_t)row * CD;
  #pragma unroll
  for (int j = 0; j < 3; j++){
    const int col = tid + j*256;
    orow[col] = f2bf((v[j] - mu)*rstd*w[col] + b[col]);
  }
}

// ---------------- bf16 MFMA GEMM: C = A(MxK) @ B(NxK)^T ----------------
// m97 structure, tile height TM in {128, 64}.
// DB=0: single buffer.  DB=1: double buffer, __syncthreads drain.
// DB=2: TRIPLE buffer + raw s_barrier + counted vmcnt(6) — tile t+1 issued at
//   iter t-1 (~2 compute phases in flight before its drain); never vmcnt(0)
//   in steady state. Buffer-overwrite safe: each buffer's readers consumed
//   their ds_reads (MFMA data-dep forces lgkmcnt) before the prior barrier.
// EPI: 0 bf16; 1 +bias+resid f32; 2 +bias f32; 3 +bias+GELU(tanh) bf16;
//      4 +bias bf16; 5 bf16 with cols<768 scaled by SCALE_LOG2E
template<int EPI, int TM, int DB>
__global__ __launch_bounds__(256) void k_gemm_bt(
    const u16* __restrict__ A, const u16* __restrict__ B,
    float* __restrict__ Cf, u16* __restrict__ Cb,
    const float* __restrict__ bias, const float* __restrict__ resid,
    int M, int N, int K){
  constexpr int NB = (DB == 2) ? 3 : (DB + 1);
  __shared__ u16 As[NB * TM * 64];
  __shared__ u16 Bs[NB * 128 * 64];
  const int tid  = threadIdx.x;
  const int lane = tid & 63;
  const int wave = tid >> 6;
  const int wr = wave >> 1, wc = wave & 1;

  // bijective XCD swizzle on flat block id
  const int gx = gridDim.x;
  const int nwg = gx * gridDim.y;
  const int orig = blockIdx.y * gx + blockIdx.x;
  const int q8 = nwg >> 3, r8 = nwg & 7;
  const int xcd = orig & 7, bse = orig >> 3;
  const int wg = (xcd < r8 ? xcd * (q8 + 1) : r8 * (q8 + 1) + (xcd - r8) * q8) + bse;
  const int m0 = (wg / gx) * TM, n0 = (wg % gx) * 128;

  f32x4 acc[TM/32][4];
  #pragma unroll
  for (int i = 0; i < TM/32; i++)
    #pragma unroll
    for (int j = 0; j < 4; j++) acc[i][j] = (f32x4){0.f, 0.f, 0.f, 0.f};

  const int lrow = lane >> 3;                     // 0..7 (row&7 of staged row)
  const int lcol = ((lane & 7) ^ lrow) * 8;       // pre-swizzled source slot
  const u16* arow = A + (size_t)(m0 + wave*(TM/4) + lrow) * K + lcol;
  const u16* brow = B + (size_t)(n0 + wave*32 + lrow) * K + lcol;

  auto STG = [&](int nb, int k0){
    #pragma unroll
    for (int i = 0; i < TM/32; i++)
      __builtin_amdgcn_global_load_lds(
        (const AS1 void*)(arow + (size_t)i*8*K + k0),
        (AS3 void*)(As + nb*TM*64 + (wave*(TM/4) + i*8)*64), 16, 0, 0);
    #pragma unroll
    for (int i = 0; i < 4; i++)
      __builtin_amdgcn_global_load_lds(
        (const AS1 void*)(brow + (size_t)i*8*K + k0),
        (AS3 void*)(Bs + nb*128*64 + (wave*32 + i*8)*64), 16, 0, 0);
  };

  auto COMPUTE = [&](int nb){
    const u16* ab = As + nb*TM*64 + (wr*(TM/2) + (lane & 15))*64;
    const u16* bb = Bs + nb*128*64 + (wc*64 + (lane & 15))*64;
    const int r7 = lane & 7;
    #pragma unroll
    for (int kk = 0; kk < 2; kk++){
      const int sl = (((lane >> 4) + 4*kk) ^ r7) * 8;   // swizzled 16B slot
      short8 af[TM/32], bfr[4];
      #pragma unroll
      for (int f = 0; f < TM/32; f++) af[f] = *(const short8*)(ab + f*1024 + sl);
      #pragma unroll
      for (int f = 0; f < 4; f++)     bfr[f] = *(const short8*)(bb + f*1024 + sl);
      #pragma unroll
      for (int i = 0; i < TM/32; i++)
        #pragma unroll
        for (int j = 0; j < 4; j++)
          acc[i][j] = __builtin_amdgcn_mfma_f32_16x16x32_bf16(af[i], bfr[j], acc[i][j], 0, 0, 0);
    }
  };

  if (DB == 2){
    const int NT = K >> 6;   // >= 3 for all uses (12 or 48)
    STG(0, 0); STG(1, 64);
    asm volatile("s_waitcnt vmcnt(6)" ::: "memory");   // tile0 landed, tile1 in flight
    __builtin_amdgcn_s_barrier();
    __builtin_amdgcn_sched_barrier(0);
    for (int it = 0; it < NT; ++it){
      const int cb = it % 3;
      if (it + 2 < NT) STG((it + 2) % 3, (it + 2) * 64);
      COMPUTE(cb);
      if (it + 2 < NT) asm volatile("s_waitcnt vmcnt(6)" ::: "memory");  // drain tile it+1 only
      else             asm volatile("s_waitcnt vmcnt(0)" ::: "memory");  // tail
      __builtin_amdgcn_s_barrier();
      __builtin_amdgcn_sched_barrier(0);
    }
  } else if (DB == 1){
    const int NT = K >> 6;
    STG(0, 0);
    __syncthreads();
    for (int it = 0; it < NT; ++it){
      const int cb = it & 1;
      if (it + 1 < NT) STG(cb ^ 1, (it + 1) * 64);
      COMPUTE(cb);
      __syncthreads();
    }
  } else {
    for (int k0 = 0; k0 < K; k0 += 64){
      STG(0, k0);
      __syncthreads();
      COMPUTE(0);
      __syncthreads();
    }
  }

  #pragma unroll
  for (int i = 0; i < TM/32; i++){
    const int rb = m0 + wr*(TM/2) + i*16 + (lane >> 4)*4;
    #pragma unroll
    for (int j = 0; j < 4; j++){
      const int col = n0 + wc*64 + j*16 + (lane & 15);
      #pragma unroll
      for (int r = 0; r < 4; r++){
        const size_t idx = (size_t)(rb + r) * N + col;
        const float v = acc[i][j][r];
        if (EPI == 0){
          Cb[idx] = f2bf(v);
        } else if (EPI == 1){
          Cf[idx] = v + bias[col] + resid[idx];
        } else if (EPI == 2){
          Cf[idx] = v + bias[col];
        } else if (EPI == 3){
          // tanh-form GELU: x * t/(t+1), t = exp(2*0.79788456*(x+0.044715x^3))
          const float gx = v + bias[col];
          const float y  = 0.79788456080286536f * (gx + 0.044715f * gx * gx * gx);
          const float t  = __expf(2.f * y);
          Cb[idx] = f2bf(gx * (t / (t + 1.f)));
        } else if (EPI == 4){
          Cb[idx] = f2bf(v + bias[col]);
        } else {
          Cb[idx] = f2bf(col < 768 ? v * SCALE_LOG2E : v);
        }
      }
    }
  }
}

// ---------------- MFMA flash attention ----------------
// Q pre-scaled by 0.125*log2e (EPI 5) -> p = exp2(sacc) directly.
// l accumulated via ones-MFMA; key-mask only at t==6; P in registers; V tr-read.
template<int MODE>
__global__ __launch_bounds__(256) void k_attn_mfma(
    const u16* __restrict__ Qb, const u16* __restrict__ Kb, const u16* __restrict__ Vb,
    u16* __restrict__ Ob, const int* __restrict__ rel_ids){
  __shared__ u16 Kl[2][2048];   // [key 32][dh 64], 16B-slot swizzle: slot ^= (key&7)
  __shared__ u16 Vl[2][2048];   // [dhblk 4][key 32][dh 16] subtiled, linear fill

  size_t qbase, kbase, vbase, obase;
  int qstr, kstr;
  if (MODE == 0){
    const int vb = blockIdx.x / H_, h = blockIdx.x % H_;
    qbase = (size_t)vb * NQ * 2304 + h * 64; qstr = 2304;
    kbase = qbase + 768; vbase = qbase + 1536; kstr = 2304;
    obase = (size_t)vb * NQ * CD + h * 64;
  } else {
    const int h = blockIdx.x % H_; int t = blockIdx.x / H_;
    const int b = t % BB; t /= BB;
    const int m = t % MV; const int vx = t / MV;
    const int rel = rel_ids[vx * MV + m];
    qbase = ((size_t)(vx * BB + b) * NQ) * CD + h * 64; qstr = CD;
    kbase = ((size_t)(rel * BB + b) * NQ) * 1536 + h * 64; kstr = 1536;
    vbase = kbase + 768;
    obase = ((size_t)((vx * MV + m) * BB + b) * NQ) * CD + h * 64;
  }

  const int tid  = threadIdx.x;
  const int lane = tid & 63;
  const int wave = tid >> 6;
  const int lq   = lane & 15;   // query-in-frag (C col)
  const int g    = lane >> 4;   // k-group

  short8 qfrag[4][2];
  #pragma unroll
  for (int qf = 0; qf < 4; qf++){
    int qrow = wave*64 + qf*16 + lq; if (qrow > 195) qrow = 195;
    const u16* qp = Qb + qbase + (size_t)qrow * qstr + g*8;
    qfrag[qf][0] = *(const short8*)(qp);
    qfrag[qf][1] = *(const short8*)(qp + 32);
  }

  union U8 { unsigned u[4]; short8 s; };

  f32x4 oacc[4][4];
  #pragma unroll
  for (int i = 0; i < 4; i++)
    #pragma unroll
    for (int j = 0; j < 4; j++) oacc[i][j] = (f32x4){0.f,0.f,0.f,0.f};
  f32x4 lacc[4];
  #pragma unroll
  for (int i = 0; i < 4; i++) lacc[i] = (f32x4){0.f,0.f,0.f,0.f};
  U8 ones;
  #pragma unroll
  for (int i = 0; i < 4; i++) ones.u[i] = 0x3F803F80u;  // bf16 1.0 pair

  const int skey  = tid >> 3;
  const int sslot = (tid & 7) ^ (skey & 7);
  const int vkey = lane >> 1;
  const int vdh  = wave*16 + (lane & 1)*8;

  auto STAGE = [&](int nb, int t0n){
    int kg = t0n + skey; if (kg > 195) kg = 195;
    __builtin_amdgcn_global_load_lds(
        (const AS1 void*)(Kb + kbase + (size_t)kg*kstr + sslot*8),
        (AS3 void*)(&Kl[nb][wave*512]), 16, 0, 0);
    int vg = t0n + vkey; if (vg > 195) vg = 195;
    __builtin_amdgcn_global_load_lds(
        (const AS1 void*)(Vb + vbase + (size_t)vg*kstr + vdh),
        (AS3 void*)(&Vl[nb][wave*512]), 16, 0, 0);
  };

  STAGE(0, 0);
  __syncthreads();

  for (int t = 0; t < 7; t++){
    const int cb = t & 1;
    const int t0 = t * 32;
    if (t < 6) STAGE(cb ^ 1, t0 + 32);

    // ---- S^T tile: 32 keys x 64 queries per wave ----
    f32x4 sacc[4][2];
    #pragma unroll
    for (int qf = 0; qf < 4; qf++)
      #pragma unroll
      for (int kf = 0; kf < 2; kf++) sacc[qf][kf] = (f32x4){0.f,0.f,0.f,0.f};
    __builtin_amdgcn_s_setprio(1);
    #pragma unroll
    for (int kf = 0; kf < 2; kf++){
      const int key = kf*16 + lq;
      #pragma unroll
      for (int ks = 0; ks < 2; ks++){
        short8 kfrag = *(const short8*)(&Kl[cb][key*64 + (((ks<<2) + g) ^ (key & 7))*8]);
        #pragma unroll
        for (int qf = 0; qf < 4; qf++)
          sacc[qf][kf] = __builtin_amdgcn_mfma_f32_16x16x32_bf16(kfrag, qfrag[qf][ks], sacc[qf][kf], 0, 0, 0);
      }
    }
    __builtin_amdgcn_s_setprio(0);

    // ---- issue V^T hardware-transpose reads (consumed after qf==0 softmax) ----
    const AS3 u16* vp = (const AS3 u16*)(&Vl[cb][0]) + (size_t)lane*4;
    uint2 tr0a, tr0b, tr1a, tr1b, tr2a, tr2b, tr3a, tr3b;
    asm volatile("ds_read_b64_tr_b16 %0, %1 offset:0"    : "=&v"(tr0a) : "v"(vp));
    asm volatile("ds_read_b64_tr_b16 %0, %1 offset:512"  : "=&v"(tr0b) : "v"(vp));
    asm volatile("ds_read_b64_tr_b16 %0, %1 offset:1024" : "=&v"(tr1a) : "v"(vp));
    asm volatile("ds_read_b64_tr_b16 %0, %1 offset:1536" : "=&v"(tr1b) : "v"(vp));
    asm volatile("ds_read_b64_tr_b16 %0, %1 offset:2048" : "=&v"(tr2a) : "v"(vp));
    asm volatile("ds_read_b64_tr_b16 %0, %1 offset:2560" : "=&v"(tr2b) : "v"(vp));
    asm volatile("ds_read_b64_tr_b16 %0, %1 offset:3072" : "=&v"(tr3a) : "v"(vp));
    asm volatile("ds_read_b64_tr_b16 %0, %1 offset:3584" : "=&v"(tr3b) : "v"(vp));

    short8 vfrag[4];
    #pragma unroll
    for (int qf = 0; qf < 4; qf++){
      // ---- softmax numerator: p = exp2(s) (scale pre-folded into Q) ----
      float p[8];
      #pragma unroll
      for (int kf = 0; kf < 2; kf++)
        #pragma unroll
        for (int r = 0; r < 4; r++)
          p[kf*4 + r] = exp2f(sacc[qf][kf][r]);
      if (t == 6){   // wave-uniform: mask keys 196..223 on the last tile only
        #pragma unroll
        for (int kf = 0; kf < 2; kf++)
          #pragma unroll
          for (int r = 0; r < 4; r++)
            if (192 + kf*16 + g*4 + r >= NQ) p[kf*4 + r] = 0.f;
      }
      U8 pk;
      pk.u[0] = (f2u(p[0]) >> 16) | (f2u(p[1]) & 0xffff0000u);
      pk.u[1] = (f2u(p[2]) >> 16) | (f2u(p[3]) & 0xffff0000u);
      pk.u[2] = (f2u(p[4]) >> 16) | (f2u(p[5]) & 0xffff0000u);
      pk.u[3] = (f2u(p[6]) >> 16) | (f2u(p[7]) & 0xffff0000u);

      if (qf == 0){
        asm volatile("s_waitcnt lgkmcnt(0)" ::: "memory");
        __builtin_amdgcn_sched_barrier(0);
        U8 v0; v0.u[0]=tr0a.x; v0.u[1]=tr0a.y; v0.u[2]=tr0b.x; v0.u[3]=tr0b.y; vfrag[0]=v0.s;
        U8 v1; v1.u[0]=tr1a.x; v1.u[1]=tr1a.y; v1.u[2]=tr1b.x; v1.u[3]=tr1b.y; vfrag[1]=v1.s;
        U8 v2; v2.u[0]=tr2a.x; v2.u[1]=tr2a.y; v2.u[2]=tr2b.x; v2.u[3]=tr2b.y; vfrag[2]=v2.s;
        U8 v3; v3.u[0]=tr3a.x; v3.u[1]=tr3a.y; v3.u[2]=tr3b.x; v3.u[3]=tr3b.y; vfrag[3]=v3.s;
      }
      // ---- O^T += mfma(V^T, P^T); l += mfma(ones, P^T) ----
      __builtin_amdgcn_s_setprio(1);
      #pragma unroll
      for (int dhf = 0; dhf < 4; dhf++)
        oacc[qf][dhf] = __builtin_amdgcn_mfma_f32_16x16x32_bf16(vfrag[dhf], pk.s, oacc[qf][dhf], 0, 0, 0);
      lacc[qf] = __builtin_amdgcn_mfma_f32_16x16x32_bf16(ones.s, pk.s, lacc[qf], 0, 0, 0);
      __builtin_amdgcn_s_setprio(0);
    }
    __syncthreads();
  }

  // ---- epilogue: divide by l (lacc row-broadcast), store O[q][dh] ----
  #pragma unroll
  for (int qf = 0; qf < 4; qf++){
    const int qrow = wave*64 + qf*16 + lq;
    if (qrow < 196){
      const float inv = 1.f / lacc[qf][0];
      u16* orow = Ob + obase + (size_t)qrow * CD;
      #pragma unroll
      for (int dhf = 0; dhf < 4; dhf++){
        uint2 pk;
        pk.x = (unsigned)f2bf(oacc[qf][dhf][0]*inv) | ((unsigned)f2bf(oacc[qf][dhf][1]*inv) << 16);
        pk.y = (unsigned)f2bf(oacc[qf][dhf][2]*inv) | ((unsigned)f2bf(oacc[qf][dhf][3]*inv) << 16);
        *(uint2*)(orow + dhf*16 + g*4) = pk;
      }
    }
  }
}

extern "C" void kernel_launch(void* const* d_in, const int* in_sizes, int n_in,
                              void* d_out, int out_size, void* d_ws, size_t ws_size,
                              hipStream_t stream){
  const float* xs           = (const float*)d_in[0];
  const float* ys           = (const float*)d_in[1];
  const int*   rel_ids      = (const int*)  d_in[4];
  const float* qkv_w        = (const float*)d_in[6];
  const float* attn_proj_w  = (const float*)d_in[7];
  const float* attn_proj_b  = (const float*)d_in[8];
  const float* q_w          = (const float*)d_in[9];
  const float* k_w          = (const float*)d_in[10];
  const float* v_w          = (const float*)d_in[11];
  const float* cross_proj_w = (const float*)d_in[12];
  const float* cross_proj_b = (const float*)d_in[13];
  const float* fc1_w        = (const float*)d_in[14];
  const float* fc1_b        = (const float*)d_in[15];
  const float* fc2_w        = (const float*)d_in[16];
  const float* fc2_b        = (const float*)d_in[17];
  const float* ln1_w        = (const float*)d_in[18];
  const float* ln1_b        = (const float*)d_in[19];
  const float* ln2_w        = (const float*)d_in[20];
  const float* ln2_b        = (const float*)d_in[21];
  const float* ln3_w        = (const float*)d_in[22];
  const float* ln3_b        = (const float*)d_in[23];
  const float* lny_w        = (const float*)d_in[24];
  const float* lny_b        = (const float*)d_in[25];
  float* out = (float*)d_out;

  char* ws = (char*)d_ws;
  size_t off = 0;
  auto alloc = [&](size_t bytes) -> char* {
    char* p = ws + off; off += (bytes + 255) & ~(size_t)255; return p;
  };
  u16* wb_qkv   = (u16*)alloc((size_t)2304*768*2);
  u16* wb_aproj = (u16*)alloc((size_t)768*768*2);
  u16* wb_q     = (u16*)alloc((size_t)768*768*2);
  u16* wb_kv    = (u16*)alloc((size_t)1536*768*2);   // k_w rows then v_w rows
  u16* wb_cproj = (u16*)alloc((size_t)768*768*2);
  u16* wb_fc1   = (u16*)alloc((size_t)3072*768*2);
  u16* wb_fc2   = (u16*)alloc((size_t)768*3072*2);
  float* x_ws   = (float*)alloc((size_t)ROWS*CD*4);
  u16* hbuf     = (u16*)alloc((size_t)ROWS*CD*2);
  u16* ynbuf    = (u16*)alloc((size_t)ROWS*CD*2);
  u16* o_self   = (u16*)alloc((size_t)ROWS*CD*2);
  u16* qs       = (u16*)alloc((size_t)ROWS*CD*2);
  u16* kvs      = (u16*)alloc((size_t)ROWS*1536*2);  // packed K|V rows
  u16* o_cross  = (u16*)alloc((size_t)CROSS_ROWS*CD*2);
  // time-disjoint union: qkv bf16 (28.9MB) / oproj bf16 (38.5MB) / mid bf16 (38.5MB)
  char* un = alloc((size_t)CROSS_ROWS*CD*2);
  u16* qkvbuf = (u16*)un;
  u16* oproj  = (u16*)un;
  u16* mid    = (u16*)un;

  // fused weight cast: 8 segments, one dispatch
  CastSegs segs;
  const float* srcs[8] = {qkv_w, attn_proj_w, q_w, k_w, v_w, cross_proj_w, fc1_w, fc2_w};
  u16* dsts[8] = {wb_qkv, wb_aproj, wb_q, wb_kv, wb_kv + 768*768, wb_cproj, wb_fc1, wb_fc2};
  int lens[8]  = {2304*768, 768*768, 768*768, 768*768, 768*768, 768*768, 3072*768, 3072*768};
  segs.cum[0] = 0;
  for (int i = 0; i < 8; i++){ segs.src[i] = srcs[i]; segs.dst[i] = dsts[i];
                               segs.cum[i+1] = segs.cum[i] + lens[i]; }
  k_cast_all<<<(segs.cum[8] + 255) / 256, 256, 0, stream>>>(segs);

  // ---- self attention block ----
  k_ln_bf16<<<ROWS, 256, 0, stream>>>(xs, ln1_w, ln1_b, hbuf);
  k_gemm_bt<5,128,1><<<dim3(2304/128, ROWS/128), 256, 0, stream>>>(
      hbuf, wb_qkv, nullptr, qkvbuf, nullptr, nullptr, ROWS, 2304, 768);
  k_attn_mfma<0><<<VBB * H_, 256, 0, stream>>>(qkvbuf, qkvbuf, qkvbuf, o_self, rel_ids);
  k_gemm_bt<1,64,1><<<dim3(768/128, ROWS/64), 256, 0, stream>>>(
      o_self, wb_aproj, x_ws, nullptr, attn_proj_b, xs, ROWS, 768, 768);

  // ---- cross attention block ----
  k_ln_bf16x2<<<2*ROWS, 256, 0, stream>>>(x_ws, ln2_w, ln2_b, hbuf,
                                          ys, lny_w, lny_b, ynbuf);
  k_gemm_bt<5,64,1><<<dim3(768/128, ROWS/64), 256, 0, stream>>>(
      hbuf, wb_q, nullptr, qs, nullptr, nullptr, ROWS, 768, 768);
  k_gemm_bt<0,128,1><<<dim3(1536/128, ROWS/128), 256, 0, stream>>>(
      ynbuf, wb_kv, nullptr, kvs, nullptr, nullptr, ROWS, 1536, 768);
  k_attn_mfma<1><<<VX * MV * BB * H_, 256, 0, stream>>>(qs, kvs, kvs, o_cross, rel_ids);
  k_gemm_bt<4,64,2><<<dim3(768/128, CROSS_ROWS/64), 256, 0, stream>>>(
      o_cross, wb_cproj, nullptr, oproj, cross_proj_b, nullptr, CROSS_ROWS, 768, 768);
  k_mmln<<<ROWS, 256, 0, stream>>>(oproj, x_ws, ln3_w, ln3_b, hbuf);

  // ---- MLP block ----
  k_gemm_bt<3,64,2><<<dim3(HIDD/128, ROWS/64), 256, 0, stream>>>(
      hbuf, wb_fc1, nullptr, mid, fc1_b, nullptr, ROWS, HIDD, 768);
  k_gemm_bt<1,64,1><<<dim3(768/128, ROWS/64), 256, 0, stream>>>(
      mid, wb_fc2, out, nullptr, fc2_b, x_ws, ROWS, 768, HIDD);
}

// Round 17
// 365.869 us; speedup vs baseline: 1.0540x; 1.0540x over previous
//
#include <hip/hip_runtime.h>
#include <hip/hip_bf16.h>
#include <stdint.h>
#include <math.h>

#define H_ 12
#define NQ 196
#define CD 768
#define HIDD 3072
#define VX 8
#define VY 8
#define BB 4
#define MV 4
#define VBB 32
#define ROWS 6272          // VBB*NQ
#define CROSS_ROWS 25088   // VX*MV*BB*NQ
// 0.125 * log2(e): folded into Q by the producing GEMM (EPI 5)
#define SCALE_LOG2E 0.180336880260608f

typedef __attribute__((ext_vector_type(8))) short short8;
typedef __attribute__((ext_vector_type(4))) float f32x4;
typedef __attribute__((ext_vector_type(4))) unsigned short u16x4;
typedef unsigned short u16;

#define AS1 __attribute__((address_space(1)))
#define AS3 __attribute__((address_space(3)))

__device__ __forceinline__ float bf2f(u16 u){
  union { unsigned int i; float f; } v; v.i = ((unsigned int)u) << 16; return v.f;
}
__device__ __forceinline__ u16 f2bf(float f){
  union { unsigned int i; float f; } v; v.f = f;
  return (u16)((v.i + 0x7fff + ((v.i >> 16) & 1)) >> 16);  // RNE
}
__device__ __forceinline__ unsigned int f2u(float f){
  union { unsigned int i; float f; } v; v.f = f; return v.i;
}

// ---------------- fused weight cast f32 -> bf16 (8 segments, 1 dispatch) ----------------
struct CastSegs {
  const float* src[8];
  u16* dst[8];
  int cum[9];   // cumulative element counts, cum[0]=0
};
__global__ __launch_bounds__(256) void k_cast_all(CastSegs segs){
  int i = blockIdx.x * 256 + threadIdx.x;
  if (i >= segs.cum[8]) return;
  int s = 0;
  #pragma unroll
  for (int k = 1; k < 8; k++) s += (i >= segs.cum[k]);
  const int off = i - segs.cum[s];
  segs.dst[s][off] = f2bf(segs.src[s][off]);
}

// ---------------- LayerNorm (f32 in, bf16 out), C=768 fixed ----------------
__device__ __forceinline__ void ln_row(const float* __restrict__ x,
    const float* __restrict__ w, const float* __restrict__ b,
    u16* __restrict__ out, int row, int tid){
  const float* xr = x + (size_t)row * CD;
  float v0 = xr[tid], v1 = xr[tid + 256], v2 = xr[tid + 512];
  float s  = v0 + v1 + v2;
  float s2 = v0*v0 + v1*v1 + v2*v2;
  __shared__ float red[8];
  const int lane = tid & 63, wid = tid >> 6;
  #pragma unroll
  for (int o = 32; o; o >>= 1){ s += __shfl_down(s, o); s2 += __shfl_down(s2, o); }
  if (lane == 0){ red[wid] = s; red[wid + 4] = s2; }
  __syncthreads();
  if (tid == 0){
    red[0] = red[0] + red[1] + red[2] + red[3];
    red[4] = red[4] + red[5] + red[6] + red[7];
  }
  __syncthreads();
  const float mu   = red[0] * (1.f/768.f);
  const float var  = red[4] * (1.f/768.f) - mu*mu;
  const float rstd = rsqrtf(var + 1e-5f);
  u16* orow = out + (size_t)row * CD;
  orow[tid]       = f2bf((v0 - mu)*rstd*w[tid]       + b[tid]);
  orow[tid + 256] = f2bf((v1 - mu)*rstd*w[tid + 256] + b[tid + 256]);
  orow[tid + 512] = f2bf((v2 - mu)*rstd*w[tid + 512] + b[tid + 512]);
}

__global__ __launch_bounds__(256) void k_ln_bf16(const float* __restrict__ x,
    const float* __restrict__ w, const float* __restrict__ b, u16* __restrict__ out){
  ln_row(x, w, b, out, blockIdx.x, threadIdx.x);
}

// two independent LNs in one dispatch (cross block: ln2(x) and lny(ys))
__global__ __launch_bounds__(256) void k_ln_bf16x2(
    const float* __restrict__ x0, const float* __restrict__ w0,
    const float* __restrict__ b0, u16* __restrict__ o0,
    const float* __restrict__ x1, const float* __restrict__ w1,
    const float* __restrict__ b1, u16* __restrict__ o1){
  const int bid = blockIdx.x;
  if (bid < ROWS) ln_row(x0, w0, b0, o0, bid, threadIdx.x);
  else            ln_row(x1, w1, b1, o1, bid - ROWS, threadIdx.x);
}

// ---------------- fused max-over-M + residual-add + LayerNorm ----------------
__global__ __launch_bounds__(256) void k_mmln(const u16* __restrict__ op,
    float* __restrict__ x, const float* __restrict__ w, const float* __restrict__ b,
    u16* __restrict__ out){
  const int row = blockIdx.x, tid = threadIdx.x;
  const int n = row % NQ, vb = row / NQ;
  const int vx = vb >> 2, bb = vb & 3;
  const size_t r0 = ((size_t)(vx * MV) * BB + bb) * NQ + n;  // m=0 source row
  const size_t ms = (size_t)BB * NQ;                          // row step per m
  float* xr = x + (size_t)row * CD;
  float v[3], s = 0.f, s2 = 0.f;
  #pragma unroll
  for (int j = 0; j < 3; j++){
    const int col = tid + j*256;
    float mx =        bf2f(op[(r0       ) * CD + col]);
    mx = fmaxf(mx,    bf2f(op[(r0 +   ms) * CD + col]));
    mx = fmaxf(mx,    bf2f(op[(r0 + 2*ms) * CD + col]));
    mx = fmaxf(mx,    bf2f(op[(r0 + 3*ms) * CD + col]));
    const float val = xr[col] + mx;
    xr[col] = val;
    v[j] = val;
    s += val; s2 += val*val;
  }
  __shared__ float red[8];
  const int lane = tid & 63, wid = tid >> 6;
  #pragma unroll
  for (int o = 32; o; o >>= 1){ s += __shfl_down(s, o); s2 += __shfl_down(s2, o); }
  if (lane == 0){ red[wid] = s; red[wid + 4] = s2; }
  __syncthreads();
  if (tid == 0){
    red[0] = red[0] + red[1] + red[2] + red[3];
    red[4] = red[4] + red[5] + red[6] + red[7];
  }
  __syncthreads();
  const float mu   = red[0] * (1.f/768.f);
  const float var  = red[4] * (1.f/768.f) - mu*mu;
  const float rstd = rsqrtf(var + 1e-5f);
  u16* orow = out + (size_t)row * CD;
  #pragma unroll
  for (int j = 0; j < 3; j++){
    const int col = tid + j*256;
    orow[col] = f2bf((v[j] - mu)*rstd*w[col] + b[col]);
  }
}

// ---------------- bf16 MFMA GEMM: C = A(MxK) @ B(NxK)^T ----------------
// m97 structure, tile height TM in {128, 64}; DB=1: double-buffered LDS,
// single-barrier pattern (issue stage t+1 EARLY, compute t, one sync).
// MEASURED config ledger: TM=64/DB=1 (48KB LDS, 3 blocks/CU) is best for ALL
// K=768-class GEMMs (fc1 69->58.8, fc2 65->~50). TM=128/DB=1 (64KB, 2/CU)
// loses; DB=2 (72KB) loses harder (FETCH +53%: L2 reuse collapse).
// EPI: 0 bf16; 1 +bias+resid f32; 2 +bias f32; 3 +bias+GELU(tanh) bf16;
//      4 +bias bf16; 5 bf16 with cols<768 scaled by SCALE_LOG2E
template<int EPI, int TM, int DB>
__global__ __launch_bounds__(256) void k_gemm_bt(
    const u16* __restrict__ A, const u16* __restrict__ B,
    float* __restrict__ Cf, u16* __restrict__ Cb,
    const float* __restrict__ bias, const float* __restrict__ resid,
    int M, int N, int K){
  __shared__ u16 As[(DB + 1) * TM * 64];
  __shared__ u16 Bs[(DB + 1) * 128 * 64];
  const int tid  = threadIdx.x;
  const int lane = tid & 63;
  const int wave = tid >> 6;
  const int wr = wave >> 1, wc = wave & 1;

  // bijective XCD swizzle on flat block id
  const int gx = gridDim.x;
  const int nwg = gx * gridDim.y;
  const int orig = blockIdx.y * gx + blockIdx.x;
  const int q8 = nwg >> 3, r8 = nwg & 7;
  const int xcd = orig & 7, bse = orig >> 3;
  const int wg = (xcd < r8 ? xcd * (q8 + 1) : r8 * (q8 + 1) + (xcd - r8) * q8) + bse;
  const int m0 = (wg / gx) * TM, n0 = (wg % gx) * 128;

  f32x4 acc[TM/32][4];
  #pragma unroll
  for (int i = 0; i < TM/32; i++)
    #pragma unroll
    for (int j = 0; j < 4; j++) acc[i][j] = (f32x4){0.f, 0.f, 0.f, 0.f};

  const int lrow = lane >> 3;                     // 0..7 (row&7 of staged row)
  const int lcol = ((lane & 7) ^ lrow) * 8;       // pre-swizzled source slot
  const u16* arow = A + (size_t)(m0 + wave*(TM/4) + lrow) * K + lcol;
  const u16* brow = B + (size_t)(n0 + wave*32 + lrow) * K + lcol;

  auto STG = [&](int nb, int k0){
    #pragma unroll
    for (int i = 0; i < TM/32; i++)
      __builtin_amdgcn_global_load_lds(
        (const AS1 void*)(arow + (size_t)i*8*K + k0),
        (AS3 void*)(As + nb*TM*64 + (wave*(TM/4) + i*8)*64), 16, 0, 0);
    #pragma unroll
    for (int i = 0; i < 4; i++)
      __builtin_amdgcn_global_load_lds(
        (const AS1 void*)(brow + (size_t)i*8*K + k0),
        (AS3 void*)(Bs + nb*128*64 + (wave*32 + i*8)*64), 16, 0, 0);
  };

  auto COMPUTE = [&](int nb){
    const u16* ab = As + nb*TM*64 + (wr*(TM/2) + (lane & 15))*64;
    const u16* bb = Bs + nb*128*64 + (wc*64 + (lane & 15))*64;
    const int r7 = lane & 7;
    #pragma unroll
    for (int kk = 0; kk < 2; kk++){
      const int sl = (((lane >> 4) + 4*kk) ^ r7) * 8;   // swizzled 16B slot
      short8 af[TM/32], bfr[4];
      #pragma unroll
      for (int f = 0; f < TM/32; f++) af[f] = *(const short8*)(ab + f*1024 + sl);
      #pragma unroll
      for (int f = 0; f < 4; f++)     bfr[f] = *(const short8*)(bb + f*1024 + sl);
      #pragma unroll
      for (int i = 0; i < TM/32; i++)
        #pragma unroll
        for (int j = 0; j < 4; j++)
          acc[i][j] = __builtin_amdgcn_mfma_f32_16x16x32_bf16(af[i], bfr[j], acc[i][j], 0, 0, 0);
    }
  };

  if (DB){
    const int NT = K >> 6;
    STG(0, 0);
    __syncthreads();
    for (int it = 0; it < NT; ++it){
      const int cb = it & 1;
      if (it + 1 < NT) STG(cb ^ 1, (it + 1) * 64);
      COMPUTE(cb);
      __syncthreads();
    }
  } else {
    for (int k0 = 0; k0 < K; k0 += 64){
      STG(0, k0);
      __syncthreads();
      COMPUTE(0);
      __syncthreads();
    }
  }

  #pragma unroll
  for (int i = 0; i < TM/32; i++){
    const int rb = m0 + wr*(TM/2) + i*16 + (lane >> 4)*4;
    #pragma unroll
    for (int j = 0; j < 4; j++){
      const int col = n0 + wc*64 + j*16 + (lane & 15);
      #pragma unroll
      for (int r = 0; r < 4; r++){
        const size_t idx = (size_t)(rb + r) * N + col;
        const float v = acc[i][j][r];
        if (EPI == 0){
          Cb[idx] = f2bf(v);
        } else if (EPI == 1){
          Cf[idx] = v + bias[col] + resid[idx];
        } else if (EPI == 2){
          Cf[idx] = v + bias[col];
        } else if (EPI == 3){
          // tanh-form GELU: x * t/(t+1), t = exp(2*0.79788456*(x+0.044715x^3))
          const float gx = v + bias[col];
          const float y  = 0.79788456080286536f * (gx + 0.044715f * gx * gx * gx);
          const float t  = __expf(2.f * y);
          Cb[idx] = f2bf(gx * (t / (t + 1.f)));
        } else if (EPI == 4){
          Cb[idx] = f2bf(v + bias[col]);
        } else {
          Cb[idx] = f2bf(col < 768 ? v * SCALE_LOG2E : v);
        }
      }
    }
  }
}

// ---------------- MFMA flash attention ----------------
// Q pre-scaled by 0.125*log2e (EPI 5) -> p = exp2(sacc) directly.
// l accumulated via ones-MFMA; key-mask only at t==6; P in registers; V tr-read.
template<int MODE>
__global__ __launch_bounds__(256) void k_attn_mfma(
    const u16* __restrict__ Qb, const u16* __restrict__ Kb, const u16* __restrict__ Vb,
    u16* __restrict__ Ob, const int* __restrict__ rel_ids){
  __shared__ u16 Kl[2][2048];   // [key 32][dh 64], 16B-slot swizzle: slot ^= (key&7)
  __shared__ u16 Vl[2][2048];   // [dhblk 4][key 32][dh 16] subtiled, linear fill

  size_t qbase, kbase, vbase, obase;
  int qstr, kstr;
  if (MODE == 0){
    const int vb = blockIdx.x / H_, h = blockIdx.x % H_;
    qbase = (size_t)vb * NQ * 2304 + h * 64; qstr = 2304;
    kbase = qbase + 768; vbase = qbase + 1536; kstr = 2304;
    obase = (size_t)vb * NQ * CD + h * 64;
  } else {
    const int h = blockIdx.x % H_; int t = blockIdx.x / H_;
    const int b = t % BB; t /= BB;
    const int m = t % MV; const int vx = t / MV;
    const int rel = rel_ids[vx * MV + m];
    qbase = ((size_t)(vx * BB + b) * NQ) * CD + h * 64; qstr = CD;
    kbase = ((size_t)(rel * BB + b) * NQ) * 1536 + h * 64; kstr = 1536;
    vbase = kbase + 768;
    obase = ((size_t)((vx * MV + m) * BB + b) * NQ) * CD + h * 64;
  }

  const int tid  = threadIdx.x;
  const int lane = tid & 63;
  const int wave = tid >> 6;
  const int lq   = lane & 15;   // query-in-frag (C col)
  const int g    = lane >> 4;   // k-group

  short8 qfrag[4][2];
  #pragma unroll
  for (int qf = 0; qf < 4; qf++){
    int qrow = wave*64 + qf*16 + lq; if (qrow > 195) qrow = 195;
    const u16* qp = Qb + qbase + (size_t)qrow * qstr + g*8;
    qfrag[qf][0] = *(const short8*)(qp);
    qfrag[qf][1] = *(const short8*)(qp + 32);
  }

  union U8 { unsigned u[4]; short8 s; };

  f32x4 oacc[4][4];
  #pragma unroll
  for (int i = 0; i < 4; i++)
    #pragma unroll
    for (int j = 0; j < 4; j++) oacc[i][j] = (f32x4){0.f,0.f,0.f,0.f};
  f32x4 lacc[4];
  #pragma unroll
  for (int i = 0; i < 4; i++) lacc[i] = (f32x4){0.f,0.f,0.f,0.f};
  U8 ones;
  #pragma unroll
  for (int i = 0; i < 4; i++) ones.u[i] = 0x3F803F80u;  // bf16 1.0 pair

  const int skey  = tid >> 3;
  const int sslot = (tid & 7) ^ (skey & 7);
  const int vkey = lane >> 1;
  const int vdh  = wave*16 + (lane & 1)*8;

  auto STAGE = [&](int nb, int t0n){
    int kg = t0n + skey; if (kg > 195) kg = 195;
    __builtin_amdgcn_global_load_lds(
        (const AS1 void*)(Kb + kbase + (size_t)kg*kstr + sslot*8),
        (AS3 void*)(&Kl[nb][wave*512]), 16, 0, 0);
    int vg = t0n + vkey; if (vg > 195) vg = 195;
    __builtin_amdgcn_global_load_lds(
        (const AS1 void*)(Vb + vbase + (size_t)vg*kstr + vdh),
        (AS3 void*)(&Vl[nb][wave*512]), 16, 0, 0);
  };

  STAGE(0, 0);
  __syncthreads();

  for (int t = 0; t < 7; t++){
    const int cb = t & 1;
    const int t0 = t * 32;
    if (t < 6) STAGE(cb ^ 1, t0 + 32);

    // ---- S^T tile: 32 keys x 64 queries per wave ----
    f32x4 sacc[4][2];
    #pragma unroll
    for (int qf = 0; qf < 4; qf++)
      #pragma unroll
      for (int kf = 0; kf < 2; kf++) sacc[qf][kf] = (f32x4){0.f,0.f,0.f,0.f};
    __builtin_amdgcn_s_setprio(1);
    #pragma unroll
    for (int kf = 0; kf < 2; kf++){
      const int key = kf*16 + lq;
      #pragma unroll
      for (int ks = 0; ks < 2; ks++){
        short8 kfrag = *(const short8*)(&Kl[cb][key*64 + (((ks<<2) + g) ^ (key & 7))*8]);
        #pragma unroll
        for (int qf = 0; qf < 4; qf++)
          sacc[qf][kf] = __builtin_amdgcn_mfma_f32_16x16x32_bf16(kfrag, qfrag[qf][ks], sacc[qf][kf], 0, 0, 0);
      }
    }
    __builtin_amdgcn_s_setprio(0);

    // ---- issue V^T hardware-transpose reads (consumed after qf==0 softmax) ----
    const AS3 u16* vp = (const AS3 u16*)(&Vl[cb][0]) + (size_t)lane*4;
    uint2 tr0a, tr0b, tr1a, tr1b, tr2a, tr2b, tr3a, tr3b;
    asm volatile("ds_read_b64_tr_b16 %0, %1 offset:0"    : "=&v"(tr0a) : "v"(vp));
    asm volatile("ds_read_b64_tr_b16 %0, %1 offset:512"  : "=&v"(tr0b) : "v"(vp));
    asm volatile("ds_read_b64_tr_b16 %0, %1 offset:1024" : "=&v"(tr1a) : "v"(vp));
    asm volatile("ds_read_b64_tr_b16 %0, %1 offset:1536" : "=&v"(tr1b) : "v"(vp));
    asm volatile("ds_read_b64_tr_b16 %0, %1 offset:2048" : "=&v"(tr2a) : "v"(vp));
    asm volatile("ds_read_b64_tr_b16 %0, %1 offset:2560" : "=&v"(tr2b) : "v"(vp));
    asm volatile("ds_read_b64_tr_b16 %0, %1 offset:3072" : "=&v"(tr3a) : "v"(vp));
    asm volatile("ds_read_b64_tr_b16 %0, %1 offset:3584" : "=&v"(tr3b) : "v"(vp));

    short8 vfrag[4];
    #pragma unroll
    for (int qf = 0; qf < 4; qf++){
      // ---- softmax numerator: p = exp2(s) (scale pre-folded into Q) ----
      float p[8];
      #pragma unroll
      for (int kf = 0; kf < 2; kf++)
        #pragma unroll
        for (int r = 0; r < 4; r++)
          p[kf*4 + r] = exp2f(sacc[qf][kf][r]);
      if (t == 6){   // wave-uniform: mask keys 196..223 on the last tile only
        #pragma unroll
        for (int kf = 0; kf < 2; kf++)
          #pragma unroll
          for (int r = 0; r < 4; r++)
            if (192 + kf*16 + g*4 + r >= NQ) p[kf*4 + r] = 0.f;
      }
      U8 pk;
      pk.u[0] = (f2u(p[0]) >> 16) | (f2u(p[1]) & 0xffff0000u);
      pk.u[1] = (f2u(p[2]) >> 16) | (f2u(p[3]) & 0xffff0000u);
      pk.u[2] = (f2u(p[4]) >> 16) | (f2u(p[5]) & 0xffff0000u);
      pk.u[3] = (f2u(p[6]) >> 16) | (f2u(p[7]) & 0xffff0000u);

      if (qf == 0){
        asm volatile("s_waitcnt lgkmcnt(0)" ::: "memory");
        __builtin_amdgcn_sched_barrier(0);
        U8 v0; v0.u[0]=tr0a.x; v0.u[1]=tr0a.y; v0.u[2]=tr0b.x; v0.u[3]=tr0b.y; vfrag[0]=v0.s;
        U8 v1; v1.u[0]=tr1a.x; v1.u[1]=tr1a.y; v1.u[2]=tr1b.x; v1.u[3]=tr1b.y; vfrag[1]=v1.s;
        U8 v2; v2.u[0]=tr2a.x; v2.u[1]=tr2a.y; v2.u[2]=tr2b.x; v2.u[3]=tr2b.y; vfrag[2]=v2.s;
        U8 v3; v3.u[0]=tr3a.x; v3.u[1]=tr3a.y; v3.u[2]=tr3b.x; v3.u[3]=tr3b.y; vfrag[3]=v3.s;
      }
      // ---- O^T += mfma(V^T, P^T); l += mfma(ones, P^T) ----
      __builtin_amdgcn_s_setprio(1);
      #pragma unroll
      for (int dhf = 0; dhf < 4; dhf++)
        oacc[qf][dhf] = __builtin_amdgcn_mfma_f32_16x16x32_bf16(vfrag[dhf], pk.s, oacc[qf][dhf], 0, 0, 0);
      lacc[qf] = __builtin_amdgcn_mfma_f32_16x16x32_bf16(ones.s, pk.s, lacc[qf], 0, 0, 0);
      __builtin_amdgcn_s_setprio(0);
    }
    __syncthreads();
  }

  // ---- epilogue: divide by l (lacc row-broadcast), store O[q][dh] ----
  #pragma unroll
  for (int qf = 0; qf < 4; qf++){
    const int qrow = wave*64 + qf*16 + lq;
    if (qrow < 196){
      const float inv = 1.f / lacc[qf][0];
      u16* orow = Ob + obase + (size_t)qrow * CD;
      #pragma unroll
      for (int dhf = 0; dhf < 4; dhf++){
        uint2 pk;
        pk.x = (unsigned)f2bf(oacc[qf][dhf][0]*inv) | ((unsigned)f2bf(oacc[qf][dhf][1]*inv) << 16);
        pk.y = (unsigned)f2bf(oacc[qf][dhf][2]*inv) | ((unsigned)f2bf(oacc[qf][dhf][3]*inv) << 16);
        *(uint2*)(orow + dhf*16 + g*4) = pk;
      }
    }
  }
}

extern "C" void kernel_launch(void* const* d_in, const int* in_sizes, int n_in,
                              void* d_out, int out_size, void* d_ws, size_t ws_size,
                              hipStream_t stream){
  const float* xs           = (const float*)d_in[0];
  const float* ys           = (const float*)d_in[1];
  const int*   rel_ids      = (const int*)  d_in[4];
  const float* qkv_w        = (const float*)d_in[6];
  const float* attn_proj_w  = (const float*)d_in[7];
  const float* attn_proj_b  = (const float*)d_in[8];
  const float* q_w          = (const float*)d_in[9];
  const float* k_w          = (const float*)d_in[10];
  const float* v_w          = (const float*)d_in[11];
  const float* cross_proj_w = (const float*)d_in[12];
  const float* cross_proj_b = (const float*)d_in[13];
  const float* fc1_w        = (const float*)d_in[14];
  const float* fc1_b        = (const float*)d_in[15];
  const float* fc2_w        = (const float*)d_in[16];
  const float* fc2_b        = (const float*)d_in[17];
  const float* ln1_w        = (const float*)d_in[18];
  const float* ln1_b        = (const float*)d_in[19];
  const float* ln2_w        = (const float*)d_in[20];
  const float* ln2_b        = (const float*)d_in[21];
  const float* ln3_w        = (const float*)d_in[22];
  const float* ln3_b        = (const float*)d_in[23];
  const float* lny_w        = (const float*)d_in[24];
  const float* lny_b        = (const float*)d_in[25];
  float* out = (float*)d_out;

  char* ws = (char*)d_ws;
  size_t off = 0;
  auto alloc = [&](size_t bytes) -> char* {
    char* p = ws + off; off += (bytes + 255) & ~(size_t)255; return p;
  };
  u16* wb_qkv   = (u16*)alloc((size_t)2304*768*2);
  u16* wb_aproj = (u16*)alloc((size_t)768*768*2);
  u16* wb_q     = (u16*)alloc((size_t)768*768*2);
  u16* wb_kv    = (u16*)alloc((size_t)1536*768*2);   // k_w rows then v_w rows
  u16* wb_cproj = (u16*)alloc((size_t)768*768*2);
  u16* wb_fc1   = (u16*)alloc((size_t)3072*768*2);
  u16* wb_fc2   = (u16*)alloc((size_t)768*3072*2);
  float* x_ws   = (float*)alloc((size_t)ROWS*CD*4);
  u16* hbuf     = (u16*)alloc((size_t)ROWS*CD*2);
  u16* ynbuf    = (u16*)alloc((size_t)ROWS*CD*2);
  u16* o_self   = (u16*)alloc((size_t)ROWS*CD*2);
  u16* qs       = (u16*)alloc((size_t)ROWS*CD*2);
  u16* kvs      = (u16*)alloc((size_t)ROWS*1536*2);  // packed K|V rows
  u16* o_cross  = (u16*)alloc((size_t)CROSS_ROWS*CD*2);
  // time-disjoint union: qkv bf16 (28.9MB) / oproj bf16 (38.5MB) / mid bf16 (38.5MB)
  char* un = alloc((size_t)CROSS_ROWS*CD*2);
  u16* qkvbuf = (u16*)un;
  u16* oproj  = (u16*)un;
  u16* mid    = (u16*)un;

  // fused weight cast: 8 segments, one dispatch
  CastSegs segs;
  const float* srcs[8] = {qkv_w, attn_proj_w, q_w, k_w, v_w, cross_proj_w, fc1_w, fc2_w};
  u16* dsts[8] = {wb_qkv, wb_aproj, wb_q, wb_kv, wb_kv + 768*768, wb_cproj, wb_fc1, wb_fc2};
  int lens[8]  = {2304*768, 768*768, 768*768, 768*768, 768*768, 768*768, 3072*768, 3072*768};
  segs.cum[0] = 0;
  for (int i = 0; i < 8; i++){ segs.src[i] = srcs[i]; segs.dst[i] = dsts[i];
                               segs.cum[i+1] = segs.cum[i] + lens[i]; }
  k_cast_all<<<(segs.cum[8] + 255) / 256, 256, 0, stream>>>(segs);

  // ---- self attention block ----
  k_ln_bf16<<<ROWS, 256, 0, stream>>>(xs, ln1_w, ln1_b, hbuf);
  k_gemm_bt<5,64,1><<<dim3(2304/128, ROWS/64), 256, 0, stream>>>(
      hbuf, wb_qkv, nullptr, qkvbuf, nullptr, nullptr, ROWS, 2304, 768);
  k_attn_mfma<0><<<VBB * H_, 256, 0, stream>>>(qkvbuf, qkvbuf, qkvbuf, o_self, rel_ids);
  k_gemm_bt<1,64,1><<<dim3(768/128, ROWS/64), 256, 0, stream>>>(
      o_self, wb_aproj, x_ws, nullptr, attn_proj_b, xs, ROWS, 768, 768);

  // ---- cross attention block ----
  k_ln_bf16x2<<<2*ROWS, 256, 0, stream>>>(x_ws, ln2_w, ln2_b, hbuf,
                                          ys, lny_w, lny_b, ynbuf);
  k_gemm_bt<5,64,1><<<dim3(768/128, ROWS/64), 256, 0, stream>>>(
      hbuf, wb_q, nullptr, qs, nullptr, nullptr, ROWS, 768, 768);
  k_gemm_bt<0,64,1><<<dim3(1536/128, ROWS/64), 256, 0, stream>>>(
      ynbuf, wb_kv, nullptr, kvs, nullptr, nullptr, ROWS, 1536, 768);
  k_attn_mfma<1><<<VX * MV * BB * H_, 256, 0, stream>>>(qs, kvs, kvs, o_cross, rel_ids);
  k_gemm_bt<4,64,1><<<dim3(768/128, CROSS_ROWS/64), 256, 0, stream>>>(
      o_cross, wb_cproj, nullptr, oproj, cross_proj_b, nullptr, CROSS_ROWS, 768, 768);
  k_mmln<<<ROWS, 256, 0, stream>>>(oproj, x_ws, ln3_w, ln3_b, hbuf);

  // ---- MLP block ----
  k_gemm_bt<3,64,1><<<dim3(HIDD/128, ROWS/64), 256, 0, stream>>>(
      hbuf, wb_fc1, nullptr, mid, fc1_b, nullptr, ROWS, HIDD, 768);
  k_gemm_bt<1,64,1><<<dim3(768/128, ROWS/64), 256, 0, stream>>>(
      mid, wb_fc2, out, nullptr, fc2_b, x_ws, ROWS, 768, HIDD);
}

// Round 18
// 364.631 us; speedup vs baseline: 1.0576x; 1.0034x over previous
//
#include <hip/hip_runtime.h>
#include <hip/hip_bf16.h>
#include <stdint.h>
#include <math.h>

#define H_ 12
#define NQ 196
#define CD 768
#define HIDD 3072
#define VX 8
#define VY 8
#define BB 4
#define MV 4
#define VBB 32
#define ROWS 6272          // VBB*NQ
#define CROSS_ROWS 25088   // VX*MV*BB*NQ
// 0.125 * log2(e): folded into Q by the producing GEMM
#define SCALE_LOG2E 0.180336880260608f

typedef __attribute__((ext_vector_type(8))) short short8;
typedef __attribute__((ext_vector_type(4))) float f32x4;
typedef __attribute__((ext_vector_type(4))) unsigned short u16x4;
typedef unsigned short u16;

#define AS1 __attribute__((address_space(1)))
#define AS3 __attribute__((address_space(3)))

__device__ __forceinline__ float bf2f(u16 u){
  union { unsigned int i; float f; } v; v.i = ((unsigned int)u) << 16; return v.f;
}
__device__ __forceinline__ u16 f2bf(float f){
  union { unsigned int i; float f; } v; v.f = f;
  return (u16)((v.i + 0x7fff + ((v.i >> 16) & 1)) >> 16);  // RNE
}
__device__ __forceinline__ unsigned int f2u(float f){
  union { unsigned int i; float f; } v; v.f = f; return v.i;
}

// ---------------- weight-cast segments ----------------
struct CastSegs {
  const float* src[8];
  u16* dst[8];
  int cum[9];   // cumulative element counts, cum[0]=0
};

// ---------------- LayerNorm row helper (f32 in, bf16 out), C=768 ----------------
__device__ __forceinline__ void ln_row(const float* __restrict__ x,
    const float* __restrict__ w, const float* __restrict__ b,
    u16* __restrict__ out, int row, int tid){
  const float* xr = x + (size_t)row * CD;
  float v0 = xr[tid], v1 = xr[tid + 256], v2 = xr[tid + 512];
  float s  = v0 + v1 + v2;
  float s2 = v0*v0 + v1*v1 + v2*v2;
  __shared__ float red[8];
  const int lane = tid & 63, wid = tid >> 6;
  #pragma unroll
  for (int o = 32; o; o >>= 1){ s += __shfl_down(s, o); s2 += __shfl_down(s2, o); }
  if (lane == 0){ red[wid] = s; red[wid + 4] = s2; }
  __syncthreads();
  if (tid == 0){
    red[0] = red[0] + red[1] + red[2] + red[3];
    red[4] = red[4] + red[5] + red[6] + red[7];
  }
  __syncthreads();
  const float mu   = red[0] * (1.f/768.f);
  const float var  = red[4] * (1.f/768.f) - mu*mu;
  const float rstd = rsqrtf(var + 1e-5f);
  u16* orow = out + (size_t)row * CD;
  orow[tid]       = f2bf((v0 - mu)*rstd*w[tid]       + b[tid]);
  orow[tid + 256] = f2bf((v1 - mu)*rstd*w[tid + 256] + b[tid + 256]);
  orow[tid + 512] = f2bf((v2 - mu)*rstd*w[tid + 512] + b[tid + 512]);
}

// merged: blocks [0,ROWS) run LN1; blocks >= ROWS run the 8-segment weight cast
__global__ __launch_bounds__(256) void k_cast_ln(CastSegs segs,
    const float* __restrict__ xs, const float* __restrict__ w,
    const float* __restrict__ b, u16* __restrict__ out){
  if ((int)blockIdx.x < ROWS){
    ln_row(xs, w, b, out, blockIdx.x, threadIdx.x);
    return;
  }
  int i = (blockIdx.x - ROWS) * 256 + threadIdx.x;
  if (i >= segs.cum[8]) return;
  int s = 0;
  #pragma unroll
  for (int k = 1; k < 8; k++) s += (i >= segs.cum[k]);
  const int off = i - segs.cum[s];
  segs.dst[s][off] = f2bf(segs.src[s][off]);
}

__global__ __launch_bounds__(256) void k_ln_bf16(const float* __restrict__ x,
    const float* __restrict__ w, const float* __restrict__ b, u16* __restrict__ out){
  ln_row(x, w, b, out, blockIdx.x, threadIdx.x);
}

// two independent LNs in one dispatch (cross block: ln2(x) and lny(ys))
__global__ __launch_bounds__(256) void k_ln_bf16x2(
    const float* __restrict__ x0, const float* __restrict__ w0,
    const float* __restrict__ b0, u16* __restrict__ o0,
    const float* __restrict__ x1, const float* __restrict__ w1,
    const float* __restrict__ b1, u16* __restrict__ o1){
  const int bid = blockIdx.x;
  if (bid < ROWS) ln_row(x0, w0, b0, o0, bid, threadIdx.x);
  else            ln_row(x1, w1, b1, o1, bid - ROWS, threadIdx.x);
}

// ---------------- fused max-over-M + residual-add + LayerNorm ----------------
__global__ __launch_bounds__(256) void k_mmln(const u16* __restrict__ op,
    float* __restrict__ x, const float* __restrict__ w, const float* __restrict__ b,
    u16* __restrict__ out){
  const int row = blockIdx.x, tid = threadIdx.x;
  const int n = row % NQ, vb = row / NQ;
  const int vx = vb >> 2, bb = vb & 3;
  const size_t r0 = ((size_t)(vx * MV) * BB + bb) * NQ + n;  // m=0 source row
  const size_t ms = (size_t)BB * NQ;                          // row step per m
  float* xr = x + (size_t)row * CD;
  float v[3], s = 0.f, s2 = 0.f;
  #pragma unroll
  for (int j = 0; j < 3; j++){
    const int col = tid + j*256;
    float mx =        bf2f(op[(r0       ) * CD + col]);
    mx = fmaxf(mx,    bf2f(op[(r0 +   ms) * CD + col]));
    mx = fmaxf(mx,    bf2f(op[(r0 + 2*ms) * CD + col]));
    mx = fmaxf(mx,    bf2f(op[(r0 + 3*ms) * CD + col]));
    const float val = xr[col] + mx;
    xr[col] = val;
    v[j] = val;
    s += val; s2 += val*val;
  }
  __shared__ float red[8];
  const int lane = tid & 63, wid = tid >> 6;
  #pragma unroll
  for (int o = 32; o; o >>= 1){ s += __shfl_down(s, o); s2 += __shfl_down(s2, o); }
  if (lane == 0){ red[wid] = s; red[wid + 4] = s2; }
  __syncthreads();
  if (tid == 0){
    red[0] = red[0] + red[1] + red[2] + red[3];
    red[4] = red[4] + red[5] + red[6] + red[7];
  }
  __syncthreads();
  const float mu   = red[0] * (1.f/768.f);
  const float var  = red[4] * (1.f/768.f) - mu*mu;
  const float rstd = rsqrtf(var + 1e-5f);
  u16* orow = out + (size_t)row * CD;
  #pragma unroll
  for (int j = 0; j < 3; j++){
    const int col = tid + j*256;
    orow[col] = f2bf((v[j] - mu)*rstd*w[col] + b[col]);
  }
}

// ---------------- bf16 MFMA GEMM: C = A(MxK) @ B(NxK)^T ----------------
// m97 structure, TM in {128,64}; DB=1: double-buffered LDS, single-barrier
// pattern. MEASURED: TM=64/DB=1 (48KB, 3 blocks/CU) best for all K=768 GEMMs.
// EPI: 0 bf16; 1 +bias+resid f32; 2 +bias f32; 3 +bias+GELU(tanh) bf16;
//      4 +bias bf16; 5 bf16 with cols<768 scaled by SCALE_LOG2E
template<int EPI, int TM, int DB>
__global__ __launch_bounds__(256) void k_gemm_bt(
    const u16* __restrict__ A, const u16* __restrict__ B,
    float* __restrict__ Cf, u16* __restrict__ Cb,
    const float* __restrict__ bias, const float* __restrict__ resid,
    int M, int N, int K){
  __shared__ u16 As[(DB + 1) * TM * 64];
  __shared__ u16 Bs[(DB + 1) * 128 * 64];
  const int tid  = threadIdx.x;
  const int lane = tid & 63;
  const int wave = tid >> 6;
  const int wr = wave >> 1, wc = wave & 1;

  // bijective XCD swizzle on flat block id
  const int gx = gridDim.x;
  const int nwg = gx * gridDim.y;
  const int orig = blockIdx.y * gx + blockIdx.x;
  const int q8 = nwg >> 3, r8 = nwg & 7;
  const int xcd = orig & 7, bse = orig >> 3;
  const int wg = (xcd < r8 ? xcd * (q8 + 1) : r8 * (q8 + 1) + (xcd - r8) * q8) + bse;
  const int m0 = (wg / gx) * TM, n0 = (wg % gx) * 128;

  f32x4 acc[TM/32][4];
  #pragma unroll
  for (int i = 0; i < TM/32; i++)
    #pragma unroll
    for (int j = 0; j < 4; j++) acc[i][j] = (f32x4){0.f, 0.f, 0.f, 0.f};

  const int lrow = lane >> 3;                     // 0..7 (row&7 of staged row)
  const int lcol = ((lane & 7) ^ lrow) * 8;       // pre-swizzled source slot
  const u16* arow = A + (size_t)(m0 + wave*(TM/4) + lrow) * K + lcol;
  const u16* brow = B + (size_t)(n0 + wave*32 + lrow) * K + lcol;

  auto STG = [&](int nb, int k0){
    #pragma unroll
    for (int i = 0; i < TM/32; i++)
      __builtin_amdgcn_global_load_lds(
        (const AS1 void*)(arow + (size_t)i*8*K + k0),
        (AS3 void*)(As + nb*TM*64 + (wave*(TM/4) + i*8)*64), 16, 0, 0);
    #pragma unroll
    for (int i = 0; i < 4; i++)
      __builtin_amdgcn_global_load_lds(
        (const AS1 void*)(brow + (size_t)i*8*K + k0),
        (AS3 void*)(Bs + nb*128*64 + (wave*32 + i*8)*64), 16, 0, 0);
  };

  auto COMPUTE = [&](int nb){
    const u16* ab = As + nb*TM*64 + (wr*(TM/2) + (lane & 15))*64;
    const u16* bb = Bs + nb*128*64 + (wc*64 + (lane & 15))*64;
    const int r7 = lane & 7;
    #pragma unroll
    for (int kk = 0; kk < 2; kk++){
      const int sl = (((lane >> 4) + 4*kk) ^ r7) * 8;   // swizzled 16B slot
      short8 af[TM/32], bfr[4];
      #pragma unroll
      for (int f = 0; f < TM/32; f++) af[f] = *(const short8*)(ab + f*1024 + sl);
      #pragma unroll
      for (int f = 0; f < 4; f++)     bfr[f] = *(const short8*)(bb + f*1024 + sl);
      #pragma unroll
      for (int i = 0; i < TM/32; i++)
        #pragma unroll
        for (int j = 0; j < 4; j++)
          acc[i][j] = __builtin_amdgcn_mfma_f32_16x16x32_bf16(af[i], bfr[j], acc[i][j], 0, 0, 0);
    }
  };

  if (DB){
    const int NT = K >> 6;
    STG(0, 0);
    __syncthreads();
    for (int it = 0; it < NT; ++it){
      const int cb = it & 1;
      if (it + 1 < NT) STG(cb ^ 1, (it + 1) * 64);
      COMPUTE(cb);
      __syncthreads();
    }
  } else {
    for (int k0 = 0; k0 < K; k0 += 64){
      STG(0, k0);
      __syncthreads();
      COMPUTE(0);
      __syncthreads();
    }
  }

  #pragma unroll
  for (int i = 0; i < TM/32; i++){
    const int rb = m0 + wr*(TM/2) + i*16 + (lane >> 4)*4;
    #pragma unroll
    for (int j = 0; j < 4; j++){
      const int col = n0 + wc*64 + j*16 + (lane & 15);
      #pragma unroll
      for (int r = 0; r < 4; r++){
        const size_t idx = (size_t)(rb + r) * N + col;
        const float v = acc[i][j][r];
        if (EPI == 0){
          Cb[idx] = f2bf(v);
        } else if (EPI == 1){
          Cf[idx] = v + bias[col] + resid[idx];
        } else if (EPI == 2){
          Cf[idx] = v + bias[col];
        } else if (EPI == 3){
          // tanh-form GELU: x * t/(t+1), t = exp(2*0.79788456*(x+0.044715x^3))
          const float gx2 = v + bias[col];
          const float y  = 0.79788456080286536f * (gx2 + 0.044715f * gx2 * gx2 * gx2);
          const float t  = __expf(2.f * y);
          Cb[idx] = f2bf(gx2 * (t / (t + 1.f)));
        } else if (EPI == 4){
          Cb[idx] = f2bf(v + bias[col]);
        } else {
          Cb[idx] = f2bf(col < 768 ? v * SCALE_LOG2E : v);
        }
      }
    }
  }
}

// ---------------- merged cross-Q + cross-KV GEMM (one dispatch) ----------------
// grid 18 x 98: logical cols 0..5 -> Q segment (A=hbuf, C=qs, N=768, *scale),
// cols 6..17 -> KV segment (A=ynbuf, C=kvs, N=1536). Segment select is after
// the XCD swizzle and wave-uniform. TM=64, DB=1 (measured-best config).
__global__ __launch_bounds__(256) void k_gemm_qx(
    const u16* __restrict__ Aq, const u16* __restrict__ Akv,
    u16* __restrict__ Cq, u16* __restrict__ Ckv, int K){
  __shared__ u16 As[2 * 64 * 64];
  __shared__ u16 Bs[2 * 128 * 64];
  const int tid  = threadIdx.x;
  const int lane = tid & 63;
  const int wave = tid >> 6;
  const int wr = wave >> 1, wc = wave & 1;

  const int gx = gridDim.x;                    // 18
  const int nwg = gx * gridDim.y;
  const int orig = blockIdx.y * gx + blockIdx.x;
  const int q8 = nwg >> 3, r8 = nwg & 7;
  const int xcd = orig & 7, bse = orig >> 3;
  const int wg = (xcd < r8 ? xcd * (q8 + 1) : r8 * (q8 + 1) + (xcd - r8) * q8) + bse;
  const int m0 = (wg / gx) * 64;
  const int xc = wg % gx;
  const bool isQ = xc < 6;
  const u16* A  = isQ ? Aq : Akv;
  const u16* B  = isQ ? Cq : Ckv;   // placeholder; B set below via weight ptrs
  u16* C        = isQ ? Cq : Ckv;
  const int N   = isQ ? 768 : 1536;
  const int n0  = (isQ ? xc : xc - 6) * 128;
  (void)B;

  f32x4 acc[2][4];
  #pragma unroll
  for (int i = 0; i < 2; i++)
    #pragma unroll
    for (int j = 0; j < 4; j++) acc[i][j] = (f32x4){0.f, 0.f, 0.f, 0.f};

  const int lrow = lane >> 3;
  const int lcol = ((lane & 7) ^ lrow) * 8;
  const u16* arow = A + (size_t)(m0 + wave*16 + lrow) * K + lcol;
  // weights are appended behind this kernel's B pointers by the caller:
  // we receive them via Cq/Ckv? No — pass weights through constant params:
  // (weights bound below in launch wrapper via global pointers)
  // -- handled by wb pointers passed in A-space: see k_gemm_qx_launch.
  // To keep this self-contained we re-derive: not possible; instead the
  // caller passes weight pointers via the unused args. (See launch.)
  // This function body is replaced by the templated variant below.
  (void)arow; (void)acc; (void)wr; (void)wc; (void)n0; (void)N; (void)C;
}

// real merged kernel with explicit weight pointers
__global__ __launch_bounds__(256) void k_gemm_qx2(
    const u16* __restrict__ Aq, const u16* __restrict__ Wq, u16* __restrict__ Cq,
    const u16* __restrict__ Akv, const u16* __restrict__ Wkv, u16* __restrict__ Ckv,
    int K){
  __shared__ u16 As[2 * 64 * 64];
  __shared__ u16 Bs[2 * 128 * 64];
  const int tid  = threadIdx.x;
  const int lane = tid & 63;
  const int wave = tid >> 6;
  const int wr = wave >> 1, wc = wave & 1;

  const int gx = gridDim.x;                    // 18
  const int nwg = gx * gridDim.y;
  const int orig = blockIdx.y * gx + blockIdx.x;
  const int q8 = nwg >> 3, r8 = nwg & 7;
  const int xcd = orig & 7, bse = orig >> 3;
  const int wg = (xcd < r8 ? xcd * (q8 + 1) : r8 * (q8 + 1) + (xcd - r8) * q8) + bse;
  const int m0 = (wg / gx) * 64;
  const int xc = wg % gx;
  const bool isQ = xc < 6;
  const u16* A  = isQ ? Aq  : Akv;
  const u16* W  = isQ ? Wq  : Wkv;
  u16* C        = isQ ? Cq  : Ckv;
  const int N   = isQ ? 768 : 1536;
  const int n0  = (isQ ? xc : xc - 6) * 128;
  const float scale = isQ ? SCALE_LOG2E : 1.f;

  f32x4 acc[2][4];
  #pragma unroll
  for (int i = 0; i < 2; i++)
    #pragma unroll
    for (int j = 0; j < 4; j++) acc[i][j] = (f32x4){0.f, 0.f, 0.f, 0.f};

  const int lrow = lane >> 3;
  const int lcol = ((lane & 7) ^ lrow) * 8;
  const u16* arow = A + (size_t)(m0 + wave*16 + lrow) * K + lcol;
  const u16* brow = W + (size_t)(n0 + wave*32 + lrow) * K + lcol;

  auto STG = [&](int nb, int k0){
    #pragma unroll
    for (int i = 0; i < 2; i++)
      __builtin_amdgcn_global_load_lds(
        (const AS1 void*)(arow + (size_t)i*8*K + k0),
        (AS3 void*)(As + nb*64*64 + (wave*16 + i*8)*64), 16, 0, 0);
    #pragma unroll
    for (int i = 0; i < 4; i++)
      __builtin_amdgcn_global_load_lds(
        (const AS1 void*)(brow + (size_t)i*8*K + k0),
        (AS3 void*)(Bs + nb*128*64 + (wave*32 + i*8)*64), 16, 0, 0);
  };

  auto COMPUTE = [&](int nb){
    const u16* ab = As + nb*64*64 + (wr*32 + (lane & 15))*64;
    const u16* bb = Bs + nb*128*64 + (wc*64 + (lane & 15))*64;
    const int r7 = lane & 7;
    #pragma unroll
    for (int kk = 0; kk < 2; kk++){
      const int sl = (((lane >> 4) + 4*kk) ^ r7) * 8;
      short8 af[2], bfr[4];
      #pragma unroll
      for (int f = 0; f < 2; f++) af[f] = *(const short8*)(ab + f*1024 + sl);
      #pragma unroll
      for (int f = 0; f < 4; f++) bfr[f] = *(const short8*)(bb + f*1024 + sl);
      #pragma unroll
      for (int i = 0; i < 2; i++)
        #pragma unroll
        for (int j = 0; j < 4; j++)
          acc[i][j] = __builtin_amdgcn_mfma_f32_16x16x32_bf16(af[i], bfr[j], acc[i][j], 0, 0, 0);
    }
  };

  const int NT = K >> 6;
  STG(0, 0);
  __syncthreads();
  for (int it = 0; it < NT; ++it){
    const int cb = it & 1;
    if (it + 1 < NT) STG(cb ^ 1, (it + 1) * 64);
    COMPUTE(cb);
    __syncthreads();
  }

  #pragma unroll
  for (int i = 0; i < 2; i++){
    const int rb = m0 + wr*32 + i*16 + (lane >> 4)*4;
    #pragma unroll
    for (int j = 0; j < 4; j++){
      const int col = n0 + wc*64 + j*16 + (lane & 15);
      #pragma unroll
      for (int r = 0; r < 4; r++)
        C[(size_t)(rb + r) * N + col] = f2bf(acc[i][j][r] * scale);
    }
  }
}

// ---------------- MFMA flash attention ----------------
// Q pre-scaled by 0.125*log2e -> p = exp2(sacc) directly.
// l accumulated via ones-MFMA; key-mask only at t==6; P in registers; V tr-read.
template<int MODE>
__global__ __launch_bounds__(256) void k_attn_mfma(
    const u16* __restrict__ Qb, const u16* __restrict__ Kb, const u16* __restrict__ Vb,
    u16* __restrict__ Ob, const int* __restrict__ rel_ids){
  __shared__ u16 Kl[2][2048];   // [key 32][dh 64], 16B-slot swizzle: slot ^= (key&7)
  __shared__ u16 Vl[2][2048];   // [dhblk 4][key 32][dh 16] subtiled, linear fill

  size_t qbase, kbase, vbase, obase;
  int qstr, kstr;
  if (MODE == 0){
    const int vb = blockIdx.x / H_, h = blockIdx.x % H_;
    qbase = (size_t)vb * NQ * 2304 + h * 64; qstr = 2304;
    kbase = qbase + 768; vbase = qbase + 1536; kstr = 2304;
    obase = (size_t)vb * NQ * CD + h * 64;
  } else {
    const int h = blockIdx.x % H_; int t = blockIdx.x / H_;
    const int b = t % BB; t /= BB;
    const int m = t % MV; const int vx = t / MV;
    const int rel = rel_ids[vx * MV + m];
    qbase = ((size_t)(vx * BB + b) * NQ) * CD + h * 64; qstr = CD;
    kbase = ((size_t)(rel * BB + b) * NQ) * 1536 + h * 64; kstr = 1536;
    vbase = kbase + 768;
    obase = ((size_t)((vx * MV + m) * BB + b) * NQ) * CD + h * 64;
  }

  const int tid  = threadIdx.x;
  const int lane = tid & 63;
  const int wave = tid >> 6;
  const int lq   = lane & 15;   // query-in-frag (C col)
  const int g    = lane >> 4;   // k-group

  short8 qfrag[4][2];
  #pragma unroll
  for (int qf = 0; qf < 4; qf++){
    int qrow = wave*64 + qf*16 + lq; if (qrow > 195) qrow = 195;
    const u16* qp = Qb + qbase + (size_t)qrow * qstr + g*8;
    qfrag[qf][0] = *(const short8*)(qp);
    qfrag[qf][1] = *(const short8*)(qp + 32);
  }

  union U8 { unsigned u[4]; short8 s; };

  f32x4 oacc[4][4];
  #pragma unroll
  for (int i = 0; i < 4; i++)
    #pragma unroll
    for (int j = 0; j < 4; j++) oacc[i][j] = (f32x4){0.f,0.f,0.f,0.f};
  f32x4 lacc[4];
  #pragma unroll
  for (int i = 0; i < 4; i++) lacc[i] = (f32x4){0.f,0.f,0.f,0.f};
  U8 ones;
  #pragma unroll
  for (int i = 0; i < 4; i++) ones.u[i] = 0x3F803F80u;  // bf16 1.0 pair

  const int skey  = tid >> 3;
  const int sslot = (tid & 7) ^ (skey & 7);
  const int vkey = lane >> 1;
  const int vdh  = wave*16 + (lane & 1)*8;

  auto STAGE = [&](int nb, int t0n){
    int kg = t0n + skey; if (kg > 195) kg = 195;
    __builtin_amdgcn_global_load_lds(
        (const AS1 void*)(Kb + kbase + (size_t)kg*kstr + sslot*8),
        (AS3 void*)(&Kl[nb][wave*512]), 16, 0, 0);
    int vg = t0n + vkey; if (vg > 195) vg = 195;
    __builtin_amdgcn_global_load_lds(
        (const AS1 void*)(Vb + vbase + (size_t)vg*kstr + vdh),
        (AS3 void*)(&Vl[nb][wave*512]), 16, 0, 0);
  };

  STAGE(0, 0);
  __syncthreads();

  for (int t = 0; t < 7; t++){
    const int cb = t & 1;
    const int t0 = t * 32;
    if (t < 6) STAGE(cb ^ 1, t0 + 32);

    // ---- S^T tile: 32 keys x 64 queries per wave ----
    f32x4 sacc[4][2];
    #pragma unroll
    for (int qf = 0; qf < 4; qf++)
      #pragma unroll
      for (int kf = 0; kf < 2; kf++) sacc[qf][kf] = (f32x4){0.f,0.f,0.f,0.f};
    __builtin_amdgcn_s_setprio(1);
    #pragma unroll
    for (int kf = 0; kf < 2; kf++){
      const int key = kf*16 + lq;
      #pragma unroll
      for (int ks = 0; ks < 2; ks++){
        short8 kfrag = *(const short8*)(&Kl[cb][key*64 + (((ks<<2) + g) ^ (key & 7))*8]);
        #pragma unroll
        for (int qf = 0; qf < 4; qf++)
          sacc[qf][kf] = __builtin_amdgcn_mfma_f32_16x16x32_bf16(kfrag, qfrag[qf][ks], sacc[qf][kf], 0, 0, 0);
      }
    }
    __builtin_amdgcn_s_setprio(0);

    // ---- issue V^T hardware-transpose reads (consumed after qf==0 softmax) ----
    const AS3 u16* vp = (const AS3 u16*)(&Vl[cb][0]) + (size_t)lane*4;
    uint2 tr0a, tr0b, tr1a, tr1b, tr2a, tr2b, tr3a, tr3b;
    asm volatile("ds_read_b64_tr_b16 %0, %1 offset:0"    : "=&v"(tr0a) : "v"(vp));
    asm volatile("ds_read_b64_tr_b16 %0, %1 offset:512"  : "=&v"(tr0b) : "v"(vp));
    asm volatile("ds_read_b64_tr_b16 %0, %1 offset:1024" : "=&v"(tr1a) : "v"(vp));
    asm volatile("ds_read_b64_tr_b16 %0, %1 offset:1536" : "=&v"(tr1b) : "v"(vp));
    asm volatile("ds_read_b64_tr_b16 %0, %1 offset:2048" : "=&v"(tr2a) : "v"(vp));
    asm volatile("ds_read_b64_tr_b16 %0, %1 offset:2560" : "=&v"(tr2b) : "v"(vp));
    asm volatile("ds_read_b64_tr_b16 %0, %1 offset:3072" : "=&v"(tr3a) : "v"(vp));
    asm volatile("ds_read_b64_tr_b16 %0, %1 offset:3584" : "=&v"(tr3b) : "v"(vp));

    short8 vfrag[4];
    #pragma unroll
    for (int qf = 0; qf < 4; qf++){
      // ---- softmax numerator: p = exp2(s) (scale pre-folded into Q) ----
      float p[8];
      #pragma unroll
      for (int kf = 0; kf < 2; kf++)
        #pragma unroll
        for (int r = 0; r < 4; r++)
          p[kf*4 + r] = exp2f(sacc[qf][kf][r]);
      if (t == 6){   // wave-uniform: mask keys 196..223 on the last tile only
        #pragma unroll
        for (int kf = 0; kf < 2; kf++)
          #pragma unroll
          for (int r = 0; r < 4; r++)
            if (192 + kf*16 + g*4 + r >= NQ) p[kf*4 + r] = 0.f;
      }
      U8 pk;
      pk.u[0] = (f2u(p[0]) >> 16) | (f2u(p[1]) & 0xffff0000u);
      pk.u[1] = (f2u(p[2]) >> 16) | (f2u(p[3]) & 0xffff0000u);
      pk.u[2] = (f2u(p[4]) >> 16) | (f2u(p[5]) & 0xffff0000u);
      pk.u[3] = (f2u(p[6]) >> 16) | (f2u(p[7]) & 0xffff0000u);

      if (qf == 0){
        asm volatile("s_waitcnt lgkmcnt(0)" ::: "memory");
        __builtin_amdgcn_sched_barrier(0);
        U8 v0; v0.u[0]=tr0a.x; v0.u[1]=tr0a.y; v0.u[2]=tr0b.x; v0.u[3]=tr0b.y; vfrag[0]=v0.s;
        U8 v1; v1.u[0]=tr1a.x; v1.u[1]=tr1a.y; v1.u[2]=tr1b.x; v1.u[3]=tr1b.y; vfrag[1]=v1.s;
        U8 v2; v2.u[0]=tr2a.x; v2.u[1]=tr2a.y; v2.u[2]=tr2b.x; v2.u[3]=tr2b.y; vfrag[2]=v2.s;
        U8 v3; v3.u[0]=tr3a.x; v3.u[1]=tr3a.y; v3.u[2]=tr3b.x; v3.u[3]=tr3b.y; vfrag[3]=v3.s;
      }
      // ---- O^T += mfma(V^T, P^T); l += mfma(ones, P^T) ----
      __builtin_amdgcn_s_setprio(1);
      #pragma unroll
      for (int dhf = 0; dhf < 4; dhf++)
        oacc[qf][dhf] = __builtin_amdgcn_mfma_f32_16x16x32_bf16(vfrag[dhf], pk.s, oacc[qf][dhf], 0, 0, 0);
      lacc[qf] = __builtin_amdgcn_mfma_f32_16x16x32_bf16(ones.s, pk.s, lacc[qf], 0, 0, 0);
      __builtin_amdgcn_s_setprio(0);
    }
    __syncthreads();
  }

  // ---- epilogue: divide by l (lacc row-broadcast), store O[q][dh] ----
  #pragma unroll
  for (int qf = 0; qf < 4; qf++){
    const int qrow = wave*64 + qf*16 + lq;
    if (qrow < 196){
      const float inv = 1.f / lacc[qf][0];
      u16* orow = Ob + obase + (size_t)qrow * CD;
      #pragma unroll
      for (int dhf = 0; dhf < 4; dhf++){
        uint2 pk;
        pk.x = (unsigned)f2bf(oacc[qf][dhf][0]*inv) | ((unsigned)f2bf(oacc[qf][dhf][1]*inv) << 16);
        pk.y = (unsigned)f2bf(oacc[qf][dhf][2]*inv) | ((unsigned)f2bf(oacc[qf][dhf][3]*inv) << 16);
        *(uint2*)(orow + dhf*16 + g*4) = pk;
      }
    }
  }
}

extern "C" void kernel_launch(void* const* d_in, const int* in_sizes, int n_in,
                              void* d_out, int out_size, void* d_ws, size_t ws_size,
                              hipStream_t stream){
  const float* xs           = (const float*)d_in[0];
  const float* ys           = (const float*)d_in[1];
  const int*   rel_ids      = (const int*)  d_in[4];
  const float* qkv_w        = (const float*)d_in[6];
  const float* attn_proj_w  = (const float*)d_in[7];
  const float* attn_proj_b  = (const float*)d_in[8];
  const float* q_w          = (const float*)d_in[9];
  const float* k_w          = (const float*)d_in[10];
  const float* v_w          = (const float*)d_in[11];
  const float* cross_proj_w = (const float*)d_in[12];
  const float* cross_proj_b = (const float*)d_in[13];
  const float* fc1_w        = (const float*)d_in[14];
  const float* fc1_b        = (const float*)d_in[15];
  const float* fc2_w        = (const float*)d_in[16];
  const float* fc2_b        = (const float*)d_in[17];
  const float* ln1_w        = (const float*)d_in[18];
  const float* ln1_b        = (const float*)d_in[19];
  const float* ln2_w        = (const float*)d_in[20];
  const float* ln2_b        = (const float*)d_in[21];
  const float* ln3_w        = (const float*)d_in[22];
  const float* ln3_b        = (const float*)d_in[23];
  const float* lny_w        = (const float*)d_in[24];
  const float* lny_b        = (const float*)d_in[25];
  float* out = (float*)d_out;

  char* ws = (char*)d_ws;
  size_t off = 0;
  auto alloc = [&](size_t bytes) -> char* {
    char* p = ws + off; off += (bytes + 255) & ~(size_t)255; return p;
  };
  u16* wb_qkv   = (u16*)alloc((size_t)2304*768*2);
  u16* wb_aproj = (u16*)alloc((size_t)768*768*2);
  u16* wb_q     = (u16*)alloc((size_t)768*768*2);
  u16* wb_kv    = (u16*)alloc((size_t)1536*768*2);   // k_w rows then v_w rows
  u16* wb_cproj = (u16*)alloc((size_t)768*768*2);
  u16* wb_fc1   = (u16*)alloc((size_t)3072*768*2);
  u16* wb_fc2   = (u16*)alloc((size_t)768*3072*2);
  float* x_ws   = (float*)alloc((size_t)ROWS*CD*4);
  u16* hbuf     = (u16*)alloc((size_t)ROWS*CD*2);
  u16* ynbuf    = (u16*)alloc((size_t)ROWS*CD*2);
  u16* o_self   = (u16*)alloc((size_t)ROWS*CD*2);
  u16* qs       = (u16*)alloc((size_t)ROWS*CD*2);
  u16* kvs      = (u16*)alloc((size_t)ROWS*1536*2);  // packed K|V rows
  u16* o_cross  = (u16*)alloc((size_t)CROSS_ROWS*CD*2);
  // time-disjoint union: qkv bf16 (28.9MB) / oproj bf16 (38.5MB) / mid bf16 (38.5MB)
  char* un = alloc((size_t)CROSS_ROWS*CD*2);
  u16* qkvbuf = (u16*)un;
  u16* oproj  = (u16*)un;
  u16* mid    = (u16*)un;

  // ---- merged weight cast + LN1 (one dispatch) ----
  CastSegs segs;
  const float* srcs[8] = {qkv_w, attn_proj_w, q_w, k_w, v_w, cross_proj_w, fc1_w, fc2_w};
  u16* dsts[8] = {wb_qkv, wb_aproj, wb_q, wb_kv, wb_kv + 768*768, wb_cproj, wb_fc1, wb_fc2};
  int lens[8]  = {2304*768, 768*768, 768*768, 768*768, 768*768, 768*768, 3072*768, 3072*768};
  segs.cum[0] = 0;
  for (int i = 0; i < 8; i++){ segs.src[i] = srcs[i]; segs.dst[i] = dsts[i];
                               segs.cum[i+1] = segs.cum[i] + lens[i]; }
  const int castBlocks = (segs.cum[8] + 255) / 256;
  k_cast_ln<<<ROWS + castBlocks, 256, 0, stream>>>(segs, xs, ln1_w, ln1_b, hbuf);

  // ---- self attention block ----
  k_gemm_bt<5,64,1><<<dim3(2304/128, ROWS/64), 256, 0, stream>>>(
      hbuf, wb_qkv, nullptr, qkvbuf, nullptr, nullptr, ROWS, 2304, 768);
  k_attn_mfma<0><<<VBB * H_, 256, 0, stream>>>(qkvbuf, qkvbuf, qkvbuf, o_self, rel_ids);
  k_gemm_bt<1,64,1><<<dim3(768/128, ROWS/64), 256, 0, stream>>>(
      o_self, wb_aproj, x_ws, nullptr, attn_proj_b, xs, ROWS, 768, 768);

  // ---- cross attention block ----
  k_ln_bf16x2<<<2*ROWS, 256, 0, stream>>>(x_ws, ln2_w, ln2_b, hbuf,
                                          ys, lny_w, lny_b, ynbuf);
  // merged cross-Q + cross-KV GEMM: 18x98 grid (Q cols 0..5, KV cols 6..17)
  k_gemm_qx2<<<dim3(18, ROWS/64), 256, 0, stream>>>(
      hbuf, wb_q, qs, ynbuf, wb_kv, kvs, 768);
  k_attn_mfma<1><<<VX * MV * BB * H_, 256, 0, stream>>>(qs, kvs, kvs, o_cross, rel_ids);
  k_gemm_bt<4,64,1><<<dim3(768/128, CROSS_ROWS/64), 256, 0, stream>>>(
      o_cross, wb_cproj, nullptr, oproj, cross_proj_b, nullptr, CROSS_ROWS, 768, 768);
  k_mmln<<<ROWS, 256, 0, stream>>>(oproj, x_ws, ln3_w, ln3_b, hbuf);

  // ---- MLP block ----
  k_gemm_bt<3,64,1><<<dim3(HIDD/128, ROWS/64), 256, 0, stream>>>(
      hbuf, wb_fc1, nullptr, mid, fc1_b, nullptr, ROWS, HIDD, 768);
  k_gemm_bt<1,64,1><<<dim3(768/128, ROWS/64), 256, 0, stream>>>(
      mid, wb_fc2, out, nullptr, fc2_b, x_ws, ROWS, 768, HIDD);
}

// Round 19
// 361.693 us; speedup vs baseline: 1.0662x; 1.0081x over previous
//
#include <hip/hip_runtime.h>
#include <hip/hip_bf16.h>
#include <stdint.h>
#include <math.h>

#define H_ 12
#define NQ 196
#define CD 768
#define HIDD 3072
#define VX 8
#define VY 8
#define BB 4
#define MV 4
#define VBB 32
#define ROWS 6272          // VBB*NQ
#define CROSS_ROWS 25088   // VX*MV*BB*NQ
// 0.125 * log2(e): folded into Q by the producing GEMM
#define SCALE_LOG2E 0.180336880260608f

typedef __attribute__((ext_vector_type(8))) short short8;
typedef __attribute__((ext_vector_type(4))) float f32x4;
typedef __attribute__((ext_vector_type(4))) unsigned short u16x4;
typedef unsigned short u16;

#define AS1 __attribute__((address_space(1)))
#define AS3 __attribute__((address_space(3)))

__device__ __forceinline__ float bf2f(u16 u){
  union { unsigned int i; float f; } v; v.i = ((unsigned int)u) << 16; return v.f;
}
__device__ __forceinline__ u16 f2bf(float f){
  union { unsigned int i; float f; } v; v.f = f;
  return (u16)((v.i + 0x7fff + ((v.i >> 16) & 1)) >> 16);  // RNE
}
__device__ __forceinline__ unsigned int f2u(float f){
  union { unsigned int i; float f; } v; v.f = f; return v.i;
}

// ---------------- weight-cast segments ----------------
struct CastSegs {
  const float* src[8];
  u16* dst[8];
  int cum[9];   // cumulative element counts, cum[0]=0
};

// ---------------- LayerNorm row helper (f32 in, bf16 out), C=768 ----------------
__device__ __forceinline__ void ln_row(const float* __restrict__ x,
    const float* __restrict__ w, const float* __restrict__ b,
    u16* __restrict__ out, int row, int tid){
  const float* xr = x + (size_t)row * CD;
  float v0 = xr[tid], v1 = xr[tid + 256], v2 = xr[tid + 512];
  float s  = v0 + v1 + v2;
  float s2 = v0*v0 + v1*v1 + v2*v2;
  __shared__ float red[8];
  const int lane = tid & 63, wid = tid >> 6;
  #pragma unroll
  for (int o = 32; o; o >>= 1){ s += __shfl_down(s, o); s2 += __shfl_down(s2, o); }
  if (lane == 0){ red[wid] = s; red[wid + 4] = s2; }
  __syncthreads();
  if (tid == 0){
    red[0] = red[0] + red[1] + red[2] + red[3];
    red[4] = red[4] + red[5] + red[6] + red[7];
  }
  __syncthreads();
  const float mu   = red[0] * (1.f/768.f);
  const float var  = red[4] * (1.f/768.f) - mu*mu;
  const float rstd = rsqrtf(var + 1e-5f);
  u16* orow = out + (size_t)row * CD;
  orow[tid]       = f2bf((v0 - mu)*rstd*w[tid]       + b[tid]);
  orow[tid + 256] = f2bf((v1 - mu)*rstd*w[tid + 256] + b[tid + 256]);
  orow[tid + 512] = f2bf((v2 - mu)*rstd*w[tid + 512] + b[tid + 512]);
}

// merged: blocks [0,ROWS) run LN1; blocks >= ROWS run the 8-segment weight cast
__global__ __launch_bounds__(256) void k_cast_ln(CastSegs segs,
    const float* __restrict__ xs, const float* __restrict__ w,
    const float* __restrict__ b, u16* __restrict__ out){
  if ((int)blockIdx.x < ROWS){
    ln_row(xs, w, b, out, blockIdx.x, threadIdx.x);
    return;
  }
  int i = (blockIdx.x - ROWS) * 256 + threadIdx.x;
  if (i >= segs.cum[8]) return;
  int s = 0;
  #pragma unroll
  for (int k = 1; k < 8; k++) s += (i >= segs.cum[k]);
  const int off = i - segs.cum[s];
  segs.dst[s][off] = f2bf(segs.src[s][off]);
}

// two independent LNs in one dispatch (cross block: ln2(x) and lny(ys))
__global__ __launch_bounds__(256) void k_ln_bf16x2(
    const float* __restrict__ x0, const float* __restrict__ w0,
    const float* __restrict__ b0, u16* __restrict__ o0,
    const float* __restrict__ x1, const float* __restrict__ w1,
    const float* __restrict__ b1, u16* __restrict__ o1){
  const int bid = blockIdx.x;
  if (bid < ROWS) ln_row(x0, w0, b0, o0, bid, threadIdx.x);
  else            ln_row(x1, w1, b1, o1, bid - ROWS, threadIdx.x);
}

// ---------------- fused max-over-M + residual-add + LayerNorm ----------------
__global__ __launch_bounds__(256) void k_mmln(const u16* __restrict__ op,
    float* __restrict__ x, const float* __restrict__ w, const float* __restrict__ b,
    u16* __restrict__ out){
  const int row = blockIdx.x, tid = threadIdx.x;
  const int n = row % NQ, vb = row / NQ;
  const int vx = vb >> 2, bb = vb & 3;
  const size_t r0 = ((size_t)(vx * MV) * BB + bb) * NQ + n;  // m=0 source row
  const size_t ms = (size_t)BB * NQ;                          // row step per m
  float* xr = x + (size_t)row * CD;
  float v[3], s = 0.f, s2 = 0.f;
  #pragma unroll
  for (int j = 0; j < 3; j++){
    const int col = tid + j*256;
    float mx =        bf2f(op[(r0       ) * CD + col]);
    mx = fmaxf(mx,    bf2f(op[(r0 +   ms) * CD + col]));
    mx = fmaxf(mx,    bf2f(op[(r0 + 2*ms) * CD + col]));
    mx = fmaxf(mx,    bf2f(op[(r0 + 3*ms) * CD + col]));
    const float val = xr[col] + mx;
    xr[col] = val;
    v[j] = val;
    s += val; s2 += val*val;
  }
  __shared__ float red[8];
  const int lane = tid & 63, wid = tid >> 6;
  #pragma unroll
  for (int o = 32; o; o >>= 1){ s += __shfl_down(s, o); s2 += __shfl_down(s2, o); }
  if (lane == 0){ red[wid] = s; red[wid + 4] = s2; }
  __syncthreads();
  if (tid == 0){
    red[0] = red[0] + red[1] + red[2] + red[3];
    red[4] = red[4] + red[5] + red[6] + red[7];
  }
  __syncthreads();
  const float mu   = red[0] * (1.f/768.f);
  const float var  = red[4] * (1.f/768.f) - mu*mu;
  const float rstd = rsqrtf(var + 1e-5f);
  u16* orow = out + (size_t)row * CD;
  #pragma unroll
  for (int j = 0; j < 3; j++){
    const int col = tid + j*256;
    orow[col] = f2bf((v[j] - mu)*rstd*w[col] + b[col]);
  }
}

// ---------------- bf16 MFMA GEMM, 512-thread / 8-wave: C = A(Mx K) @ B(NxK)^T ----
// Tile 64x128, waves 2x4 (each 32x32, acc[2][2]), DB=1 double buffer with the
// single-barrier pattern. LDS stays 48KB (3 blocks/CU) but 8 waves/block ->
// up to 24 waves/CU: 2x the latency-hiding pool at the same L2 footprint.
// Conflict-free XOR swizzle (both-sides), bijective XCD swizzle.
// EPI: 0 bf16; 1 +bias+resid f32; 2 +bias f32; 3 +bias+GELU(tanh) bf16;
//      4 +bias bf16; 5 bf16 with cols<768 scaled by SCALE_LOG2E
template<int EPI>
__global__ __launch_bounds__(512) void k_gemm64(
    const u16* __restrict__ A, const u16* __restrict__ B,
    float* __restrict__ Cf, u16* __restrict__ Cb,
    const float* __restrict__ bias, const float* __restrict__ resid,
    int M, int N, int K){
  __shared__ u16 As[2 * 64 * 64];    // 16KB
  __shared__ u16 Bs[2 * 128 * 64];   // 32KB
  const int tid  = threadIdx.x;
  const int lane = tid & 63;
  const int wave = tid >> 6;       // 0..7
  const int wr = wave >> 2;        // 0..1 (row half)
  const int wc = wave & 3;         // 0..3 (col quarter)

  // bijective XCD swizzle on flat block id
  const int gx = gridDim.x;
  const int nwg = gx * gridDim.y;
  const int orig = blockIdx.y * gx + blockIdx.x;
  const int q8 = nwg >> 3, r8 = nwg & 7;
  const int xcd = orig & 7, bse = orig >> 3;
  const int wg = (xcd < r8 ? xcd * (q8 + 1) : r8 * (q8 + 1) + (xcd - r8) * q8) + bse;
  const int m0 = (wg / gx) * 64, n0 = (wg % gx) * 128;

  f32x4 acc[2][2];
  #pragma unroll
  for (int i = 0; i < 2; i++)
    #pragma unroll
    for (int j = 0; j < 2; j++) acc[i][j] = (f32x4){0.f, 0.f, 0.f, 0.f};

  // staging: thread t -> row t>>3 (0..63), physical 16B slot t&7,
  // pre-swizzled global source column ((t&7) ^ (row&7))*8
  const int srow = tid >> 3;
  const int scol = ((tid & 7) ^ (srow & 7)) * 8;
  const u16* arow  = A + (size_t)(m0 + srow) * K + scol;
  const u16* brow0 = B + (size_t)(n0 + srow) * K + scol;
  const u16* brow1 = B + (size_t)(n0 + 64 + srow) * K + scol;

  auto STG = [&](int nb, int k0){
    __builtin_amdgcn_global_load_lds(
        (const AS1 void*)(arow + k0),
        (AS3 void*)(As + nb*4096 + wave*512), 16, 0, 0);
    __builtin_amdgcn_global_load_lds(
        (const AS1 void*)(brow0 + k0),
        (AS3 void*)(Bs + nb*8192 + wave*512), 16, 0, 0);
    __builtin_amdgcn_global_load_lds(
        (const AS1 void*)(brow1 + k0),
        (AS3 void*)(Bs + nb*8192 + 4096 + wave*512), 16, 0, 0);
  };

  auto COMPUTE = [&](int nb){
    const u16* ab = As + nb*4096 + (wr*32 + (lane & 15))*64;
    const u16* bb = Bs + nb*8192 + (wc*32 + (lane & 15))*64;
    const int r7 = lane & 7;
    #pragma unroll
    for (int kk = 0; kk < 2; kk++){
      const int sl = (((lane >> 4) + 4*kk) ^ r7) * 8;   // swizzled 16B slot
      short8 af[2], bfr[2];
      #pragma unroll
      for (int f = 0; f < 2; f++){
        af[f]  = *(const short8*)(ab + f*1024 + sl);
        bfr[f] = *(const short8*)(bb + f*1024 + sl);
      }
      #pragma unroll
      for (int i = 0; i < 2; i++)
        #pragma unroll
        for (int j = 0; j < 2; j++)
          acc[i][j] = __builtin_amdgcn_mfma_f32_16x16x32_bf16(af[i], bfr[j], acc[i][j], 0, 0, 0);
    }
  };

  const int NT = K >> 6;
  STG(0, 0);
  __syncthreads();
  for (int it = 0; it < NT; ++it){
    const int cb = it & 1;
    if (it + 1 < NT) STG(cb ^ 1, (it + 1) * 64);
    COMPUTE(cb);
    __syncthreads();
  }

  #pragma unroll
  for (int i = 0; i < 2; i++){
    const int rb = m0 + wr*32 + i*16 + (lane >> 4)*4;
    #pragma unroll
    for (int j = 0; j < 2; j++){
      const int col = n0 + wc*32 + j*16 + (lane & 15);
      #pragma unroll
      for (int r = 0; r < 4; r++){
        const size_t idx = (size_t)(rb + r) * N + col;
        const float v = acc[i][j][r];
        if (EPI == 0){
          Cb[idx] = f2bf(v);
        } else if (EPI == 1){
          Cf[idx] = v + bias[col] + resid[idx];
        } else if (EPI == 2){
          Cf[idx] = v + bias[col];
        } else if (EPI == 3){
          // tanh-form GELU: x * t/(t+1), t = exp(2*0.79788456*(x+0.044715x^3))
          const float gx2 = v + bias[col];
          const float y  = 0.79788456080286536f * (gx2 + 0.044715f * gx2 * gx2 * gx2);
          const float t  = __expf(2.f * y);
          Cb[idx] = f2bf(gx2 * (t / (t + 1.f)));
        } else if (EPI == 4){
          Cb[idx] = f2bf(v + bias[col]);
        } else {
          Cb[idx] = f2bf(col < 768 ? v * SCALE_LOG2E : v);
        }
      }
    }
  }
}

// ---------------- merged cross-Q + cross-KV GEMM (one dispatch, 256 thr) ------
// grid 18 x 98: cols 0..5 -> Q segment (A=hbuf, C=qs, N=768, *scale),
// cols 6..17 -> KV segment (A=ynbuf, C=kvs, N=1536). TM=64 4-wave m97 form.
__global__ __launch_bounds__(256) void k_gemm_qx2(
    const u16* __restrict__ Aq, const u16* __restrict__ Wq, u16* __restrict__ Cq,
    const u16* __restrict__ Akv, const u16* __restrict__ Wkv, u16* __restrict__ Ckv,
    int K){
  __shared__ u16 As[2 * 64 * 64];
  __shared__ u16 Bs[2 * 128 * 64];
  const int tid  = threadIdx.x;
  const int lane = tid & 63;
  const int wave = tid >> 6;
  const int wr = wave >> 1, wc = wave & 1;

  const int gx = gridDim.x;                    // 18
  const int nwg = gx * gridDim.y;
  const int orig = blockIdx.y * gx + blockIdx.x;
  const int q8 = nwg >> 3, r8 = nwg & 7;
  const int xcd = orig & 7, bse = orig >> 3;
  const int wg = (xcd < r8 ? xcd * (q8 + 1) : r8 * (q8 + 1) + (xcd - r8) * q8) + bse;
  const int m0 = (wg / gx) * 64;
  const int xc = wg % gx;
  const bool isQ = xc < 6;
  const u16* A  = isQ ? Aq  : Akv;
  const u16* W  = isQ ? Wq  : Wkv;
  u16* C        = isQ ? Cq  : Ckv;
  const int N   = isQ ? 768 : 1536;
  const int n0  = (isQ ? xc : xc - 6) * 128;
  const float scale = isQ ? SCALE_LOG2E : 1.f;

  f32x4 acc[2][4];
  #pragma unroll
  for (int i = 0; i < 2; i++)
    #pragma unroll
    for (int j = 0; j < 4; j++) acc[i][j] = (f32x4){0.f, 0.f, 0.f, 0.f};

  const int lrow = lane >> 3;
  const int lcol = ((lane & 7) ^ lrow) * 8;
  const u16* arow = A + (size_t)(m0 + wave*16 + lrow) * K + lcol;
  const u16* brow = W + (size_t)(n0 + wave*32 + lrow) * K + lcol;

  auto STG = [&](int nb, int k0){
    #pragma unroll
    for (int i = 0; i < 2; i++)
      __builtin_amdgcn_global_load_lds(
        (const AS1 void*)(arow + (size_t)i*8*K + k0),
        (AS3 void*)(As + nb*64*64 + (wave*16 + i*8)*64), 16, 0, 0);
    #pragma unroll
    for (int i = 0; i < 4; i++)
      __builtin_amdgcn_global_load_lds(
        (const AS1 void*)(brow + (size_t)i*8*K + k0),
        (AS3 void*)(Bs + nb*128*64 + (wave*32 + i*8)*64), 16, 0, 0);
  };

  auto COMPUTE = [&](int nb){
    const u16* ab = As + nb*64*64 + (wr*32 + (lane & 15))*64;
    const u16* bb = Bs + nb*128*64 + (wc*64 + (lane & 15))*64;
    const int r7 = lane & 7;
    #pragma unroll
    for (int kk = 0; kk < 2; kk++){
      const int sl = (((lane >> 4) + 4*kk) ^ r7) * 8;
      short8 af[2], bfr[4];
      #pragma unroll
      for (int f = 0; f < 2; f++) af[f] = *(const short8*)(ab + f*1024 + sl);
      #pragma unroll
      for (int f = 0; f < 4; f++) bfr[f] = *(const short8*)(bb + f*1024 + sl);
      #pragma unroll
      for (int i = 0; i < 2; i++)
        #pragma unroll
        for (int j = 0; j < 4; j++)
          acc[i][j] = __builtin_amdgcn_mfma_f32_16x16x32_bf16(af[i], bfr[j], acc[i][j], 0, 0, 0);
    }
  };

  const int NT = K >> 6;
  STG(0, 0);
  __syncthreads();
  for (int it = 0; it < NT; ++it){
    const int cb = it & 1;
    if (it + 1 < NT) STG(cb ^ 1, (it + 1) * 64);
    COMPUTE(cb);
    __syncthreads();
  }

  #pragma unroll
  for (int i = 0; i < 2; i++){
    const int rb = m0 + wr*32 + i*16 + (lane >> 4)*4;
    #pragma unroll
    for (int j = 0; j < 4; j++){
      const int col = n0 + wc*64 + j*16 + (lane & 15);
      #pragma unroll
      for (int r = 0; r < 4; r++)
        C[(size_t)(rb + r) * N + col] = f2bf(acc[i][j][r] * scale);
    }
  }
}

// ---------------- MFMA flash attention ----------------
// Q pre-scaled by 0.125*log2e -> p = exp2(sacc) directly.
// l accumulated via ones-MFMA; key-mask only at t==6; P in registers; V tr-read.
template<int MODE>
__global__ __launch_bounds__(256) void k_attn_mfma(
    const u16* __restrict__ Qb, const u16* __restrict__ Kb, const u16* __restrict__ Vb,
    u16* __restrict__ Ob, const int* __restrict__ rel_ids){
  __shared__ u16 Kl[2][2048];   // [key 32][dh 64], 16B-slot swizzle: slot ^= (key&7)
  __shared__ u16 Vl[2][2048];   // [dhblk 4][key 32][dh 16] subtiled, linear fill

  size_t qbase, kbase, vbase, obase;
  int qstr, kstr;
  if (MODE == 0){
    const int vb = blockIdx.x / H_, h = blockIdx.x % H_;
    qbase = (size_t)vb * NQ * 2304 + h * 64; qstr = 2304;
    kbase = qbase + 768; vbase = qbase + 1536; kstr = 2304;
    obase = (size_t)vb * NQ * CD + h * 64;
  } else {
    const int h = blockIdx.x % H_; int t = blockIdx.x / H_;
    const int b = t % BB; t /= BB;
    const int m = t % MV; const int vx = t / MV;
    const int rel = rel_ids[vx * MV + m];
    qbase = ((size_t)(vx * BB + b) * NQ) * CD + h * 64; qstr = CD;
    kbase = ((size_t)(rel * BB + b) * NQ) * 1536 + h * 64; kstr = 1536;
    vbase = kbase + 768;
    obase = ((size_t)((vx * MV + m) * BB + b) * NQ) * CD + h * 64;
  }

  const int tid  = threadIdx.x;
  const int lane = tid & 63;
  const int wave = tid >> 6;
  const int lq   = lane & 15;   // query-in-frag (C col)
  const int g    = lane >> 4;   // k-group

  short8 qfrag[4][2];
  #pragma unroll
  for (int qf = 0; qf < 4; qf++){
    int qrow = wave*64 + qf*16 + lq; if (qrow > 195) qrow = 195;
    const u16* qp = Qb + qbase + (size_t)qrow * qstr + g*8;
    qfrag[qf][0] = *(const short8*)(qp);
    qfrag[qf][1] = *(const short8*)(qp + 32);
  }

  union U8 { unsigned u[4]; short8 s; };

  f32x4 oacc[4][4];
  #pragma unroll
  for (int i = 0; i < 4; i++)
    #pragma unroll
    for (int j = 0; j < 4; j++) oacc[i][j] = (f32x4){0.f,0.f,0.f,0.f};
  f32x4 lacc[4];
  #pragma unroll
  for (int i = 0; i < 4; i++) lacc[i] = (f32x4){0.f,0.f,0.f,0.f};
  U8 ones;
  #pragma unroll
  for (int i = 0; i < 4; i++) ones.u[i] = 0x3F803F80u;  // bf16 1.0 pair

  const int skey  = tid >> 3;
  const int sslot = (tid & 7) ^ (skey & 7);
  const int vkey = lane >> 1;
  const int vdh  = wave*16 + (lane & 1)*8;

  auto STAGE = [&](int nb, int t0n){
    int kg = t0n + skey; if (kg > 195) kg = 195;
    __builtin_amdgcn_global_load_lds(
        (const AS1 void*)(Kb + kbase + (size_t)kg*kstr + sslot*8),
        (AS3 void*)(&Kl[nb][wave*512]), 16, 0, 0);
    int vg = t0n + vkey; if (vg > 195) vg = 195;
    __builtin_amdgcn_global_load_lds(
        (const AS1 void*)(Vb + vbase + (size_t)vg*kstr + vdh),
        (AS3 void*)(&Vl[nb][wave*512]), 16, 0, 0);
  };

  STAGE(0, 0);
  __syncthreads();

  for (int t = 0; t < 7; t++){
    const int cb = t & 1;
    const int t0 = t * 32;
    if (t < 6) STAGE(cb ^ 1, t0 + 32);

    // ---- S^T tile: 32 keys x 64 queries per wave ----
    f32x4 sacc[4][2];
    #pragma unroll
    for (int qf = 0; qf < 4; qf++)
      #pragma unroll
      for (int kf = 0; kf < 2; kf++) sacc[qf][kf] = (f32x4){0.f,0.f,0.f,0.f};
    __builtin_amdgcn_s_setprio(1);
    #pragma unroll
    for (int kf = 0; kf < 2; kf++){
      const int key = kf*16 + lq;
      #pragma unroll
      for (int ks = 0; ks < 2; ks++){
        short8 kfrag = *(const short8*)(&Kl[cb][key*64 + (((ks<<2) + g) ^ (key & 7))*8]);
        #pragma unroll
        for (int qf = 0; qf < 4; qf++)
          sacc[qf][kf] = __builtin_amdgcn_mfma_f32_16x16x32_bf16(kfrag, qfrag[qf][ks], sacc[qf][kf], 0, 0, 0);
      }
    }
    __builtin_amdgcn_s_setprio(0);

    // ---- issue V^T hardware-transpose reads (consumed after qf==0 softmax) ----
    const AS3 u16* vp = (const AS3 u16*)(&Vl[cb][0]) + (size_t)lane*4;
    uint2 tr0a, tr0b, tr1a, tr1b, tr2a, tr2b, tr3a, tr3b;
    asm volatile("ds_read_b64_tr_b16 %0, %1 offset:0"    : "=&v"(tr0a) : "v"(vp));
    asm volatile("ds_read_b64_tr_b16 %0, %1 offset:512"  : "=&v"(tr0b) : "v"(vp));
    asm volatile("ds_read_b64_tr_b16 %0, %1 offset:1024" : "=&v"(tr1a) : "v"(vp));
    asm volatile("ds_read_b64_tr_b16 %0, %1 offset:1536" : "=&v"(tr1b) : "v"(vp));
    asm volatile("ds_read_b64_tr_b16 %0, %1 offset:2048" : "=&v"(tr2a) : "v"(vp));
    asm volatile("ds_read_b64_tr_b16 %0, %1 offset:2560" : "=&v"(tr2b) : "v"(vp));
    asm volatile("ds_read_b64_tr_b16 %0, %1 offset:3072" : "=&v"(tr3a) : "v"(vp));
    asm volatile("ds_read_b64_tr_b16 %0, %1 offset:3584" : "=&v"(tr3b) : "v"(vp));

    short8 vfrag[4];
    #pragma unroll
    for (int qf = 0; qf < 4; qf++){
      // ---- softmax numerator: p = exp2(s) (scale pre-folded into Q) ----
      float p[8];
      #pragma unroll
      for (int kf = 0; kf < 2; kf++)
        #pragma unroll
        for (int r = 0; r < 4; r++)
          p[kf*4 + r] = exp2f(sacc[qf][kf][r]);
      if (t == 6){   // wave-uniform: mask keys 196..223 on the last tile only
        #pragma unroll
        for (int kf = 0; kf < 2; kf++)
          #pragma unroll
          for (int r = 0; r < 4; r++)
            if (192 + kf*16 + g*4 + r >= NQ) p[kf*4 + r] = 0.f;
      }
      U8 pk;
      pk.u[0] = (f2u(p[0]) >> 16) | (f2u(p[1]) & 0xffff0000u);
      pk.u[1] = (f2u(p[2]) >> 16) | (f2u(p[3]) & 0xffff0000u);
      pk.u[2] = (f2u(p[4]) >> 16) | (f2u(p[5]) & 0xffff0000u);
      pk.u[3] = (f2u(p[6]) >> 16) | (f2u(p[7]) & 0xffff0000u);

      if (qf == 0){
        asm volatile("s_waitcnt lgkmcnt(0)" ::: "memory");
        __builtin_amdgcn_sched_barrier(0);
        U8 v0; v0.u[0]=tr0a.x; v0.u[1]=tr0a.y; v0.u[2]=tr0b.x; v0.u[3]=tr0b.y; vfrag[0]=v0.s;
        U8 v1; v1.u[0]=tr1a.x; v1.u[1]=tr1a.y; v1.u[2]=tr1b.x; v1.u[3]=tr1b.y; vfrag[1]=v1.s;
        U8 v2; v2.u[0]=tr2a.x; v2.u[1]=tr2a.y; v2.u[2]=tr2b.x; v2.u[3]=tr2b.y; vfrag[2]=v2.s;
        U8 v3; v3.u[0]=tr3a.x; v3.u[1]=tr3a.y; v3.u[2]=tr3b.x; v3.u[3]=tr3b.y; vfrag[3]=v3.s;
      }
      // ---- O^T += mfma(V^T, P^T); l += mfma(ones, P^T) ----
      __builtin_amdgcn_s_setprio(1);
      #pragma unroll
      for (int dhf = 0; dhf < 4; dhf++)
        oacc[qf][dhf] = __builtin_amdgcn_mfma_f32_16x16x32_bf16(vfrag[dhf], pk.s, oacc[qf][dhf], 0, 0, 0);
      lacc[qf] = __builtin_amdgcn_mfma_f32_16x16x32_bf16(ones.s, pk.s, lacc[qf], 0, 0, 0);
      __builtin_amdgcn_s_setprio(0);
    }
    __syncthreads();
  }

  // ---- epilogue: divide by l (lacc row-broadcast), store O[q][dh] ----
  #pragma unroll
  for (int qf = 0; qf < 4; qf++){
    const int qrow = wave*64 + qf*16 + lq;
    if (qrow < 196){
      const float inv = 1.f / lacc[qf][0];
      u16* orow = Ob + obase + (size_t)qrow * CD;
      #pragma unroll
      for (int dhf = 0; dhf < 4; dhf++){
        uint2 pk;
        pk.x = (unsigned)f2bf(oacc[qf][dhf][0]*inv) | ((unsigned)f2bf(oacc[qf][dhf][1]*inv) << 16);
        pk.y = (unsigned)f2bf(oacc[qf][dhf][2]*inv) | ((unsigned)f2bf(oacc[qf][dhf][3]*inv) << 16);
        *(uint2*)(orow + dhf*16 + g*4) = pk;
      }
    }
  }
}

extern "C" void kernel_launch(void* const* d_in, const int* in_sizes, int n_in,
                              void* d_out, int out_size, void* d_ws, size_t ws_size,
                              hipStream_t stream){
  const float* xs           = (const float*)d_in[0];
  const float* ys           = (const float*)d_in[1];
  const int*   rel_ids      = (const int*)  d_in[4];
  const float* qkv_w        = (const float*)d_in[6];
  const float* attn_proj_w  = (const float*)d_in[7];
  const float* attn_proj_b  = (const float*)d_in[8];
  const float* q_w          = (const float*)d_in[9];
  const float* k_w          = (const float*)d_in[10];
  const float* v_w          = (const float*)d_in[11];
  const float* cross_proj_w = (const float*)d_in[12];
  const float* cross_proj_b = (const float*)d_in[13];
  const float* fc1_w        = (const float*)d_in[14];
  const float* fc1_b        = (const float*)d_in[15];
  const float* fc2_w        = (const float*)d_in[16];
  const float* fc2_b        = (const float*)d_in[17];
  const float* ln1_w        = (const float*)d_in[18];
  const float* ln1_b        = (const float*)d_in[19];
  const float* ln2_w        = (const float*)d_in[20];
  const float* ln2_b        = (const float*)d_in[21];
  const float* ln3_w        = (const float*)d_in[22];
  const float* ln3_b        = (const float*)d_in[23];
  const float* lny_w        = (const float*)d_in[24];
  const float* lny_b        = (const float*)d_in[25];
  float* out = (float*)d_out;

  char* ws = (char*)d_ws;
  size_t off = 0;
  auto alloc = [&](size_t bytes) -> char* {
    char* p = ws + off; off += (bytes + 255) & ~(size_t)255; return p;
  };
  u16* wb_qkv   = (u16*)alloc((size_t)2304*768*2);
  u16* wb_aproj = (u16*)alloc((size_t)768*768*2);
  u16* wb_q     = (u16*)alloc((size_t)768*768*2);
  u16* wb_kv    = (u16*)alloc((size_t)1536*768*2);   // k_w rows then v_w rows
  u16* wb_cproj = (u16*)alloc((size_t)768*768*2);
  u16* wb_fc1   = (u16*)alloc((size_t)3072*768*2);
  u16* wb_fc2   = (u16*)alloc((size_t)768*3072*2);
  float* x_ws   = (float*)alloc((size_t)ROWS*CD*4);
  u16* hbuf     = (u16*)alloc((size_t)ROWS*CD*2);
  u16* ynbuf    = (u16*)alloc((size_t)ROWS*CD*2);
  u16* o_self   = (u16*)alloc((size_t)ROWS*CD*2);
  u16* qs       = (u16*)alloc((size_t)ROWS*CD*2);
  u16* kvs      = (u16*)alloc((size_t)ROWS*1536*2);  // packed K|V rows
  u16* o_cross  = (u16*)alloc((size_t)CROSS_ROWS*CD*2);
  // time-disjoint union: qkv bf16 (28.9MB) / oproj bf16 (38.5MB) / mid bf16 (38.5MB)
  char* un = alloc((size_t)CROSS_ROWS*CD*2);
  u16* qkvbuf = (u16*)un;
  u16* oproj  = (u16*)un;
  u16* mid    = (u16*)un;

  // ---- merged weight cast + LN1 (one dispatch) ----
  CastSegs segs;
  const float* srcs[8] = {qkv_w, attn_proj_w, q_w, k_w, v_w, cross_proj_w, fc1_w, fc2_w};
  u16* dsts[8] = {wb_qkv, wb_aproj, wb_q, wb_kv, wb_kv + 768*768, wb_cproj, wb_fc1, wb_fc2};
  int lens[8]  = {2304*768, 768*768, 768*768, 768*768, 768*768, 768*768, 3072*768, 3072*768};
  segs.cum[0] = 0;
  for (int i = 0; i < 8; i++){ segs.src[i] = srcs[i]; segs.dst[i] = dsts[i];
                               segs.cum[i+1] = segs.cum[i] + lens[i]; }
  const int castBlocks = (segs.cum[8] + 255) / 256;
  k_cast_ln<<<ROWS + castBlocks, 256, 0, stream>>>(segs, xs, ln1_w, ln1_b, hbuf);

  // ---- self attention block ----
  k_gemm64<5><<<dim3(2304/128, ROWS/64), 512, 0, stream>>>(
      hbuf, wb_qkv, nullptr, qkvbuf, nullptr, nullptr, ROWS, 2304, 768);
  k_attn_mfma<0><<<VBB * H_, 256, 0, stream>>>(qkvbuf, qkvbuf, qkvbuf, o_self, rel_ids);
  k_gemm64<1><<<dim3(768/128, ROWS/64), 512, 0, stream>>>(
      o_self, wb_aproj, x_ws, nullptr, attn_proj_b, xs, ROWS, 768, 768);

  // ---- cross attention block ----
  k_ln_bf16x2<<<2*ROWS, 256, 0, stream>>>(x_ws, ln2_w, ln2_b, hbuf,
                                          ys, lny_w, lny_b, ynbuf);
  // merged cross-Q + cross-KV GEMM: 18x98 grid (Q cols 0..5, KV cols 6..17)
  k_gemm_qx2<<<dim3(18, ROWS/64), 256, 0, stream>>>(
      hbuf, wb_q, qs, ynbuf, wb_kv, kvs, 768);
  k_attn_mfma<1><<<VX * MV * BB * H_, 256, 0, stream>>>(qs, kvs, kvs, o_cross, rel_ids);
  k_gemm64<4><<<dim3(768/128, CROSS_ROWS/64), 512, 0, stream>>>(
      o_cross, wb_cproj, nullptr, oproj, cross_proj_b, nullptr, CROSS_ROWS, 768, 768);
  k_mmln<<<ROWS, 256, 0, stream>>>(oproj, x_ws, ln3_w, ln3_b, hbuf);

  // ---- MLP block ----
  k_gemm64<3><<<dim3(HIDD/128, ROWS/64), 512, 0, stream>>>(
      hbuf, wb_fc1, nullptr, mid, fc1_b, nullptr, ROWS, HIDD, 768);
  k_gemm64<1><<<dim3(768/128, ROWS/64), 512, 0, stream>>>(
      mid, wb_fc2, out, nullptr, fc2_b, x_ws, ROWS, 768, HIDD);
}